// Round 9
// baseline (283.789 us; speedup 1.0000x reference)
//
#include <hip/hip_runtime.h>

// Mamba block fwd: B=2, L=1024, D=1024, DIN=2048, N=16, R=64, K=4
#define LSEQ 1024
#define DMODEL 1024
#define DINNER 2048
#define NSTATE 16
#define RRANK 64
#define CHUNK 32     // timesteps per scan chunk
#define NCHUNK 32    // LSEQ / CHUNK
#define KSPLIT 8     // xproj split-K factor
#define MF (1024 * 1024)   // 1M floats

typedef unsigned short u16;
typedef __attribute__((ext_vector_type(8))) short bf16x8;   // 8 bf16 = 4 VGPRs
typedef __attribute__((ext_vector_type(4))) short bf16x4;
typedef __attribute__((ext_vector_type(4))) float f32x4;

__device__ __forceinline__ float sigmoidf_(float x) {
    return 1.0f / (1.0f + __expf(-x));
}
__device__ __forceinline__ float softplusf_(float x) {
    return (x > 20.0f) ? x : log1pf(__expf(x));
}
__device__ __forceinline__ short f2bf(float f) {
    union { float f; unsigned u; } v; v.f = f;
    unsigned r = v.u + 0x7FFF + ((v.u >> 16) & 1);   // RNE
    return (short)(r >> 16);
}
__device__ __forceinline__ float bf2f(u16 b) {
    union { unsigned u; float f; } v; v.u = ((unsigned)b) << 16;
    return v.f;
}
// Async global->LDS, 16 B per lane; LDS dest = wave-uniform base + lane*16.
__device__ __forceinline__ void async_cp16(const u16* g, u16* l) {
    __builtin_amdgcn_global_load_lds(
        (const __attribute__((address_space(1))) unsigned int*)g,
        (__attribute__((address_space(3))) unsigned int*)l, 16, 0, 0);
}

// ---------------------------------------------------------------------------
// ALL input casts in ONE dispatch:
//  seg0 (1024 blk): x [2048,1024] -> xb bf16 (flat, 8/thread)
//  seg1 (4096 blk): W_in [1024,4096] -> W_in^T bf16 [4096,1024]
//  seg2 (2048 blk): W_out [2048,1024] -> W_out^T bf16 [1024,2048]
// ---------------------------------------------------------------------------
__global__ __launch_bounds__(256) void cast_all_kernel(
    const float* __restrict__ x, u16* __restrict__ xb,
    const float* __restrict__ Win, u16* __restrict__ Wbin,
    const float* __restrict__ Wout, u16* __restrict__ Wbout)
{
    __shared__ float t[32][33];
    int bid = blockIdx.x;
    if (bid < 1024) {                               // flat cast
        const size_t i = ((size_t)bid * 256 + threadIdx.x) * 8;
        float4 a = *(const float4*)&x[i];
        float4 b = *(const float4*)&x[i + 4];
        bf16x8 o;
        o[0] = f2bf(a.x); o[1] = f2bf(a.y); o[2] = f2bf(a.z); o[3] = f2bf(a.w);
        o[4] = f2bf(b.x); o[5] = f2bf(b.y); o[6] = f2bf(b.z); o[7] = f2bf(b.w);
        *(bf16x8*)&xb[i] = o;
        return;
    }
    const float* in; u16* out; int R, C, bxi, byi;
    if (bid < 1024 + 4096) {
        int tt = bid - 1024;
        in = Win; out = Wbin; R = DMODEL; C = 2 * DINNER;
        bxi = tt & 127; byi = tt >> 7;
    } else {
        int tt = bid - 5120;
        in = Wout; out = Wbout; R = DINNER; C = DMODEL;
        bxi = tt & 31; byi = tt >> 5;
    }
    const int bx = bxi * 32, by = byi * 32;
    const int tx = threadIdx.x & 31, ty = threadIdx.x >> 5;
    #pragma unroll
    for (int i = 0; i < 4; ++i)
        t[ty + 8 * i][tx] = in[(size_t)(by + ty + 8 * i) * C + bx + tx];
    __syncthreads();
    #pragma unroll
    for (int i = 0; i < 4; ++i)
        out[(size_t)(bx + ty + 8 * i) * R + by + tx] = (u16)f2bf(t[tx][ty + 8 * i]);
}

// ---------------------------------------------------------------------------
// bf16 MFMA GEMM: A[M,K] * Bt[N,K]^T.  Async global_load_lds staging, BK=64.
// BF16OUT: bf16 to Cb (ldc=N); else fp32 to Cf.
// SWZ: XCD-aware supertile remap. HW round-robins linear block id across the
// 8 XCDs (id%8=xcd heuristic); remap so each XCD owns a CONTIGUOUS band of
// tiles whose A/B panels fit its private 4 MiB L2:
//   SWZ=1: column bands (XCD owns gx/8 tile-cols)  — for K-small/N-large
//   SWZ=2: row bands    (XCD owns gy/8 tile-rows)  — for K-large/N-small
// A/B-frag [mn=lane&15][k=quad*8+j]; C/D row=quad*4+reg, col=lane&15 (verified).
// ---------------------------------------------------------------------------
template<int BM, int BN, int BK, bool BF16OUT, int SWZ>
__global__ __launch_bounds__(256) void mfma_gemm_kernel(
    const u16* __restrict__ A, const u16* __restrict__ Bt,
    float* __restrict__ Cf, u16* __restrict__ Cb, int M, int N, int K)
{
    constexpr int WMS = BM / 32;
    constexpr int WNS = BN / 32;
    __shared__ u16 lA[BM * BK];
    __shared__ u16 lB[BN * BK];

    const int tid  = threadIdx.x;
    const int lane = tid & 63, wave = tid >> 6;
    const int quad = lane >> 4, l16 = lane & 15;
    const int wm   = (wave >> 1) * (BM / 2);
    const int wn   = (wave & 1) * (BN / 2);

    // XCD supertile swizzle
    const int gx = gridDim.x, gy = gridDim.y;
    const int id = blockIdx.x + gx * blockIdx.y;   // linear dispatch order
    const int G8 = (gx * gy) >> 3;
    const int id2 = (id & 7) * G8 + (id >> 3);     // XCD j -> contiguous band
    int bx, by;
    if (SWZ == 1)      { bx = id2 / gy; by = id2 % gy; }  // column bands
    else if (SWZ == 2) { by = id2 / gx; bx = id2 % gx; }  // row bands
    else               { bx = blockIdx.x; by = blockIdx.y; }
    const int row0 = by * BM;
    const int col0 = bx * BN;

    f32x4 acc[WMS][WNS];
    #pragma unroll
    for (int i = 0; i < WMS; ++i)
        #pragma unroll
        for (int j = 0; j < WNS; ++j)
            acc[i][j] = (f32x4){0.f, 0.f, 0.f, 0.f};

    for (int k0 = 0; k0 < K; k0 += BK) {
        #pragma unroll
        for (int t = 0; t < (BM * BK) / 2048; ++t) {     // A: 16B/lane chunks
            int c = tid + t * 256;
            int r = c / (BK / 8), kc = c % (BK / 8);
            async_cp16(&A[(size_t)(row0 + r) * K + k0 + kc * 8], &lA[c * 8]);
        }
        #pragma unroll
        for (int t = 0; t < (BN * BK) / 2048; ++t) {
            int c = tid + t * 256;
            int r = c / (BK / 8), kc = c % (BK / 8);
            async_cp16(&Bt[(size_t)(col0 + r) * K + k0 + kc * 8], &lB[c * 8]);
        }
        __syncthreads();   // vmcnt drained before barrier
        #pragma unroll
        for (int ks = 0; ks < BK; ks += 32) {
            bf16x8 af[WMS], bfr[WNS];
            #pragma unroll
            for (int i = 0; i < WMS; ++i)
                af[i] = *(bf16x8*)&lA[(wm + i * 16 + l16) * BK + ks + quad * 8];
            #pragma unroll
            for (int j = 0; j < WNS; ++j)
                bfr[j] = *(bf16x8*)&lB[(wn + j * 16 + l16) * BK + ks + quad * 8];
            #pragma unroll
            for (int i = 0; i < WMS; ++i)
                #pragma unroll
                for (int j = 0; j < WNS; ++j)
                    acc[i][j] = __builtin_amdgcn_mfma_f32_16x16x32_bf16(
                        af[i], bfr[j], acc[i][j], 0, 0, 0);
        }
        __syncthreads();
    }
    if (BF16OUT) {
        #pragma unroll
        for (int i = 0; i < WMS; ++i)
            #pragma unroll
            for (int j = 0; j < WNS; ++j)
                #pragma unroll
                for (int r = 0; r < 4; ++r)
                    Cb[(size_t)(row0 + wm + i * 16 + quad * 4 + r) * N
                       + col0 + wn + j * 16 + l16] = (u16)f2bf(acc[i][j][r]);
    } else {
        #pragma unroll
        for (int i = 0; i < WMS; ++i)
            #pragma unroll
            for (int j = 0; j < WNS; ++j)
                #pragma unroll
                for (int r = 0; r < 4; ++r)
                    Cf[(size_t)(row0 + wm + i * 16 + quad * 4 + r) * N
                       + col0 + wn + j * 16 + l16] = acc[i][j][r];
    }
}

// ---------------------------------------------------------------------------
// Causal depthwise conv (K=4) + SiLU. Reads XZb x-half (bf16, stride 4096),
// writes xconv bf16.
// ---------------------------------------------------------------------------
__global__ __launch_bounds__(256) void conv_silu_kernel(
    const u16* __restrict__ XZb, const float* __restrict__ cw,
    const float* __restrict__ cb, u16* __restrict__ xcb)
{
    const int idx = blockIdx.x * 256 + threadIdx.x;   // over B*L*(DIN/4)
    const int dq  = idx % (DINNER / 4);
    const int bl  = idx / (DINNER / 4);               // b*L + l
    const int l   = bl % LSEQ;
    const int d0  = dq * 4;

    const float4* cw4 = (const float4*)cw;
    const float4 W0 = cw4[d0 + 0];
    const float4 W1 = cw4[d0 + 1];
    const float4 W2 = cw4[d0 + 2];
    const float4 W3 = cw4[d0 + 3];
    float4 s = *(const float4*)&cb[d0];

    #pragma unroll
    for (int k = 0; k < 4; ++k) {
        int ls = l + k - 3;
        if (ls >= 0) {
            bf16x4 xv = *(const bf16x4*)&XZb[(size_t)(bl + k - 3) * (2 * DINNER) + d0];
            s.x = fmaf(bf2f((u16)xv[0]), ((const float*)&W0)[k], s.x);
            s.y = fmaf(bf2f((u16)xv[1]), ((const float*)&W1)[k], s.y);
            s.z = fmaf(bf2f((u16)xv[2]), ((const float*)&W2)[k], s.z);
            s.w = fmaf(bf2f((u16)xv[3]), ((const float*)&W3)[k], s.w);
        }
    }
    bf16x4 o;
    o[0] = f2bf(s.x * sigmoidf_(s.x));
    o[1] = f2bf(s.y * sigmoidf_(s.y));
    o[2] = f2bf(s.z * sigmoidf_(s.z));
    o[3] = f2bf(s.w * sigmoidf_(s.w));
    *(bf16x4*)&xcb[(size_t)idx * 4] = o;
}

// ---------------------------------------------------------------------------
// x_proj split-K, deterministic: each k-split writes its own partial.
// ---------------------------------------------------------------------------
__global__ __launch_bounds__(256) void xproj_part_kernel(
    const u16* __restrict__ xcb, const float* __restrict__ Wx,
    float* __restrict__ part)
{
    __shared__ float As[32][64 + 4];
    __shared__ float Ws[32][96 + 4];

    const int tid  = threadIdx.x;
    const int tx   = tid % 32;
    const int ty   = tid / 32;
    const int row0 = blockIdx.x * 64;
    const int k0   = blockIdx.y * (DINNER / KSPLIT);

    float acc[8][3];
    #pragma unroll
    for (int i = 0; i < 8; ++i) { acc[i][0] = 0.f; acc[i][1] = 0.f; acc[i][2] = 0.f; }

    for (int kt = 0; kt < DINNER / KSPLIT; kt += 32) {
        const int kb = k0 + kt;
        {   // 64 rows x 32 ks of bf16: 256 thr x 8 elems
            int m = tid >> 2, kq = tid & 3;
            bf16x8 v = *(const bf16x8*)&xcb[(size_t)(row0 + m) * DINNER + kb + kq * 8];
            #pragma unroll
            for (int j = 0; j < 8; ++j)
                As[kq * 8 + j][m] = bf2f((u16)v[j]);
        }
        #pragma unroll
        for (int i = 0; i < 3; ++i) {
            int lin = tid + i * 256;
            int kk = lin / 24, q = lin % 24;
            *(float4*)&Ws[kk][q * 4] = *(const float4*)&Wx[(size_t)(kb + kk) * 96 + q * 4];
        }
        __syncthreads();
        #pragma unroll 8
        for (int kk = 0; kk < 32; ++kk) {
            float a[8];
            *(float4*)&a[0] = *(const float4*)&As[kk][ty * 8];
            *(float4*)&a[4] = *(const float4*)&As[kk][ty * 8 + 4];
            float b0 = Ws[kk][tx], b1 = Ws[kk][tx + 32], b2 = Ws[kk][tx + 64];
            #pragma unroll
            for (int i = 0; i < 8; ++i) {
                acc[i][0] = fmaf(a[i], b0, acc[i][0]);
                acc[i][1] = fmaf(a[i], b1, acc[i][1]);
                acc[i][2] = fmaf(a[i], b2, acc[i][2]);
            }
        }
        __syncthreads();
    }
    float* po = part + (size_t)blockIdx.y * (2 * LSEQ * 96);
    #pragma unroll
    for (int i = 0; i < 8; ++i) {
        int r = row0 + ty * 8 + i;
        po[(size_t)r * 96 + tx]      = acc[i][0];
        po[(size_t)r * 96 + tx + 32] = acc[i][1];
        po[(size_t)r * 96 + tx + 64] = acc[i][2];
    }
}

// ---------------------------------------------------------------------------
// delta = softplus(dt @ W_dt + b_dt) -> bf16.  FUSED with the xproj partial
// reduction; col-block 0 also reduces the B/C cols into xBC[2048][32].
// kk loop unroll CAPPED at 8 (full unroll spilled: VGPR=256, 8x write ampl).
// ---------------------------------------------------------------------------
__global__ __launch_bounds__(256) void delta_fused_kernel(
    const float* __restrict__ part, const float* __restrict__ Wdt,
    const float* __restrict__ bdt, u16* __restrict__ deltab,
    float* __restrict__ xBC)
{
    __shared__ float As[64][64 + 4];
    __shared__ float Ws[64][64 + 4];
    const int tid  = threadIdx.x;
    const int tx   = tid % 16;
    const int ty   = tid / 16;
    const int row0 = blockIdx.y * 64;
    const int col0 = blockIdx.x * 64;

    #pragma unroll
    for (int i = 0; i < 4; ++i) {      // stage dt^T with 8-way partial sum
        int lin = tid + i * 256;
        int m = lin / 16, kq = lin % 16;
        float4 v = {0.f, 0.f, 0.f, 0.f};
        #pragma unroll
        for (int s8 = 0; s8 < KSPLIT; ++s8) {
            float4 p = *(const float4*)&part[(size_t)s8 * (2 * LSEQ * 96)
                                             + (size_t)(row0 + m) * 96 + kq * 4];
            v.x += p.x; v.y += p.y; v.z += p.z; v.w += p.w;
        }
        As[kq * 4 + 0][m] = v.x;
        As[kq * 4 + 1][m] = v.y;
        As[kq * 4 + 2][m] = v.z;
        As[kq * 4 + 3][m] = v.w;
    }
    #pragma unroll
    for (int i = 0; i < 4; ++i) {
        int lin = tid + i * 256;
        int kk = lin / 16, q = lin % 16;
        *(float4*)&Ws[kk][q * 4] = *(const float4*)&Wdt[(size_t)kk * DINNER + col0 + q * 4];
    }
    __syncthreads();

    float acc[4][4];
    #pragma unroll
    for (int i = 0; i < 4; ++i)
        #pragma unroll
        for (int j = 0; j < 4; ++j) acc[i][j] = 0.0f;

    #pragma unroll 8
    for (int kk = 0; kk < 64; ++kk) {
        float4 a = *(const float4*)&As[kk][ty * 4];
        float4 b = *(const float4*)&Ws[kk][tx * 4];
        const float* ap = (const float*)&a;
        const float* bp = (const float*)&b;
        #pragma unroll
        for (int i = 0; i < 4; ++i)
            #pragma unroll
            for (int j = 0; j < 4; ++j)
                acc[i][j] = fmaf(ap[i], bp[j], acc[i][j]);
    }

    float4 bv = *(const float4*)&bdt[col0 + tx * 4];
    const float* bvp = (const float*)&bv;
    #pragma unroll
    for (int i = 0; i < 4; ++i) {
        bf16x4 o;
        o[0] = f2bf(softplusf_(acc[i][0] + bvp[0]));
        o[1] = f2bf(softplusf_(acc[i][1] + bvp[1]));
        o[2] = f2bf(softplusf_(acc[i][2] + bvp[2]));
        o[3] = f2bf(softplusf_(acc[i][3] + bvp[3]));
        *(bf16x4*)&deltab[(size_t)(row0 + ty * 4 + i) * DINNER + col0 + tx * 4] = o;
    }

    if (blockIdx.x == 0) {             // reduce B/C cols for these 64 rows
        #pragma unroll
        for (int i = 0; i < 8; ++i) {
            int lin = tid + i * 256;   // [0, 2048)
            int r = lin >> 5, c2 = lin & 31;
            float s = 0.0f;
            #pragma unroll
            for (int s8 = 0; s8 < KSPLIT; ++s8)
                s += part[(size_t)s8 * (2 * LSEQ * 96)
                          + (size_t)(row0 + r) * 96 + RRANK + c2];
            xBC[(size_t)(row0 + r) * 32 + c2] = s;
        }
    }
}

// ---------------------------------------------------------------------------
// Chunked selective scan — channel-per-thread, N=16 states in registers.
// ---------------------------------------------------------------------------
__global__ __launch_bounds__(256) void scan_part1_kernel(
    const u16* __restrict__ deltab, const u16* __restrict__ xcb,
    const float* __restrict__ xBC, const float* __restrict__ A_log,
    float* __restrict__ Pbuf, float* __restrict__ Hbuf)
{
    const int d  = blockIdx.x * 256 + threadIdx.x;
    const int b  = blockIdx.y;
    const int ch = blockIdx.z;

    float Aa[NSTATE];
    #pragma unroll
    for (int q = 0; q < 4; ++q) {
        float4 v = *(const float4*)&A_log[(size_t)d * NSTATE + q * 4];
        Aa[q * 4 + 0] = -__expf(v.x);
        Aa[q * 4 + 1] = -__expf(v.y);
        Aa[q * 4 + 2] = -__expf(v.z);
        Aa[q * 4 + 3] = -__expf(v.w);
    }
    float h[NSTATE], P[NSTATE];
    #pragma unroll
    for (int n = 0; n < NSTATE; ++n) { h[n] = 0.0f; P[n] = 1.0f; }

    const size_t row0 = (size_t)b * LSEQ + (size_t)ch * CHUNK;
    #pragma unroll 4
    for (int t = 0; t < CHUNK; ++t) {
        const size_t row = row0 + t;
        float dv  = bf2f(deltab[row * DINNER + d]);
        float xcv = bf2f(xcb[row * DINNER + d]);
        float du  = dv * xcv;
        const float4* br = (const float4*)&xBC[row * 32];   // wave-uniform
        float4 B4[4] = { br[0], br[1], br[2], br[3] };
        const float* Bv = (const float*)B4;
        #pragma unroll
        for (int n = 0; n < NSTATE; ++n) {
            float dA = __expf(dv * Aa[n]);
            h[n] = fmaf(dA, h[n], du * Bv[n]);
            P[n] *= dA;
        }
    }
    float* Pp = &Pbuf[(((size_t)ch * 2 + b) * DINNER + d) * NSTATE];
    float* Hp = &Hbuf[(((size_t)ch * 2 + b) * DINNER + d) * NSTATE];
    #pragma unroll
    for (int q = 0; q < 4; ++q) {
        *(float4*)&Pp[q * 4] = *(float4*)&P[q * 4];
        *(float4*)&Hp[q * 4] = *(float4*)&h[q * 4];
    }
}

// Phase 2: per (b,d,n) serial prefix over chunks -> chunk-start states h0.
__global__ __launch_bounds__(256) void scan_combine_kernel(
    const float* __restrict__ Pbuf, const float* __restrict__ Hbuf,
    float* __restrict__ h0buf)
{
    const int idx = blockIdx.x * 256 + threadIdx.x;   // (b*DIN+d)*N+n
    float H = 0.0f;
    #pragma unroll 8
    for (int cch = 0; cch < NCHUNK; ++cch) {
        const size_t g = (size_t)cch * (2 * DINNER * NSTATE) + idx;
        h0buf[g] = H;
        H = fmaf(Pbuf[g], H, Hbuf[g]);
    }
}

// Phase 3: resweep from h0; y = sum_n h[n]*C[n]; +D-skip, *silu(z); y -> bf16.
__global__ __launch_bounds__(256) void scan_part2_kernel(
    const u16* __restrict__ deltab, const u16* __restrict__ xcb,
    const float* __restrict__ xBC, const float* __restrict__ h0buf,
    const u16* __restrict__ XZb, u16* __restrict__ yb,
    const float* __restrict__ A_log, const float* __restrict__ Dskip)
{
    const int d  = blockIdx.x * 256 + threadIdx.x;
    const int b  = blockIdx.y;
    const int ch = blockIdx.z;

    float Aa[NSTATE];
    #pragma unroll
    for (int q = 0; q < 4; ++q) {
        float4 v = *(const float4*)&A_log[(size_t)d * NSTATE + q * 4];
        Aa[q * 4 + 0] = -__expf(v.x);
        Aa[q * 4 + 1] = -__expf(v.y);
        Aa[q * 4 + 2] = -__expf(v.z);
        Aa[q * 4 + 3] = -__expf(v.w);
    }
    const float Dd = Dskip[d];

    float h[NSTATE];
    const float* Hp = &h0buf[(((size_t)ch * 2 + b) * DINNER + d) * NSTATE];
    #pragma unroll
    for (int q = 0; q < 4; ++q)
        *(float4*)&h[q * 4] = *(const float4*)&Hp[q * 4];

    const size_t row0 = (size_t)b * LSEQ + (size_t)ch * CHUNK;
    #pragma unroll 2
    for (int t = 0; t < CHUNK; ++t) {
        const size_t row = row0 + t;
        float dv  = bf2f(deltab[row * DINNER + d]);
        float xcv = bf2f(xcb[row * DINNER + d]);
        float du  = dv * xcv;
        const float4* br = (const float4*)&xBC[row * 32];   // wave-uniform
        float4 BC[8] = { br[0], br[1], br[2], br[3], br[4], br[5], br[6], br[7] };
        const float* Bv = (const float*)BC;
        const float* Cv = Bv + NSTATE;
        float y = 0.0f;
        #pragma unroll
        for (int n = 0; n < NSTATE; ++n) {
            float dA = __expf(dv * Aa[n]);
            h[n] = fmaf(dA, h[n], du * Bv[n]);
            y = fmaf(h[n], Cv[n], y);
        }
        float zz = bf2f(XZb[row * (2 * DINNER) + DINNER + d]);
        float yv = (y + xcv * Dd) * (zz * sigmoidf_(zz));
        yb[row * DINNER + d] = (u16)f2bf(yv);
    }
}

// ---------------------------------------------------------------------------
// Post LayerNorm over D=1024. One block per row.
// ---------------------------------------------------------------------------
__global__ __launch_bounds__(256) void ln_kernel(
    const float* __restrict__ t, const float* __restrict__ g,
    const float* __restrict__ b, float* __restrict__ out)
{
    const int row = blockIdx.x;
    const int tid = threadIdx.x;
    float4 v = *(const float4*)&t[(size_t)row * DMODEL + tid * 4];
    float s = v.x + v.y + v.z + v.w;
    float q = v.x * v.x + v.y * v.y + v.z * v.z + v.w * v.w;
    #pragma unroll
    for (int m = 1; m < 64; m <<= 1) {
        s += __shfl_xor(s, m, 64);
        q += __shfl_xor(q, m, 64);
    }
    __shared__ float ss[4], qq[4];
    if ((tid & 63) == 0) { ss[tid >> 6] = s; qq[tid >> 6] = q; }
    __syncthreads();
    float S = ss[0] + ss[1] + ss[2] + ss[3];
    float Q = qq[0] + qq[1] + qq[2] + qq[3];
    float mu  = S * (1.0f / DMODEL);
    float var = Q * (1.0f / DMODEL) - mu * mu;
    float rs  = rsqrtf(var + 1e-5f);
    float4 gv = *(const float4*)&g[tid * 4];
    float4 bv = *(const float4*)&b[tid * 4];
    float4 o;
    o.x = (v.x - mu) * rs * gv.x + bv.x;
    o.y = (v.y - mu) * rs * gv.y + bv.y;
    o.z = (v.z - mu) * rs * gv.z + bv.z;
    o.w = (v.w - mu) * rs * gv.w + bv.w;
    *(float4*)&out[(size_t)row * DMODEL + tid * 4] = o;
}

// ---------------------------------------------------------------------------
extern "C" void kernel_launch(void* const* d_in, const int* in_sizes, int n_in,
                              void* d_out, int out_size, void* d_ws, size_t ws_size,
                              hipStream_t stream) {
    const float* x      = (const float*)d_in[0];
    const float* W_in   = (const float*)d_in[1];
    const float* conv_w = (const float*)d_in[2];
    const float* conv_b = (const float*)d_in[3];
    const float* W_x    = (const float*)d_in[4];
    const float* W_dt   = (const float*)d_in[5];
    const float* b_dt   = (const float*)d_in[6];
    const float* A_log  = (const float*)d_in[7];
    const float* D_skip = (const float*)d_in[8];
    const float* W_out  = (const float*)d_in[9];
    const float* ln_g   = (const float*)d_in[10];
    const float* ln_b   = (const float*)d_in[11];
    (void)in_sizes; (void)n_in; (void)out_size; (void)ws_size;

    const int M = 2 * LSEQ;  // B*L = 2048

    // Workspace layout (float offsets). 18M floats + 64K = ~72.5 MB.
    float* ws     = (float*)d_ws;
    u16*   XZb    = (u16*)ws;                 // [0,4M f)   in_proj out bf16 (dead after scan2)
    u16*   xcb    = (u16*)(ws + 4 * MF);      // [4M,6M)    xconv bf16       (dead after scan2)
    u16*   deltab = (u16*)(ws + 6 * MF);      // [6M,8M)    delta bf16       (dead after scan2)
    float* part   = ws + 8 * (size_t)MF;      // [8M,9.5M)  xproj partials   (dead after delta)
    float* Pbuf   = ws + 8 * (size_t)MF;      // [8M,10M)   after part dead
    float* Hbuf   = ws + 10 * (size_t)MF;     // [10M,12M)
    float* h0     = ws + 12 * (size_t)MF;     // [12M,14M)
    u16*   xb     = (u16*)(ws + 14 * MF);     // [14M,15M)  x bf16 (dead after in_proj)
    u16*   Wbin   = (u16*)(ws + 15 * MF);     // [15M,17M)  W_in^T (dead after in_proj)
    u16*   Wbout  = (u16*)(ws + 17 * MF);     // [17M,18M)
    float* xBC    = ws + 18 * (size_t)MF;     // [18M,+64K) reduced B/C fp32
    u16*   yb     = (u16*)(ws + 15 * MF);     // Wbin region (y bf16, after scan2)
    float* pout   = ws;                       // [0,2M f) out_proj fp32 (over dead XZb)

    // 0) all casts, one dispatch
    cast_all_kernel<<<1024 + 4096 + 2048, 256, 0, stream>>>(
        x, xb, W_in, Wbin, W_out, Wbout);

    // 1) in_proj: XZb = xb @ W_in^T, bf16 out, 512 blocks, COLUMN-band swizzle
    //    (per XCD: 4 B-panels 1MB + A 4MB ~= fits private L2)
    mfma_gemm_kernel<128, 128, 64, true, 1>
        <<<dim3((2 * DINNER) / 128, M / 128), 256, 0, stream>>>(
            xb, Wbin, nullptr, XZb, M, 2 * DINNER, DMODEL);

    // 2) causal depthwise conv + silu (bf16 in/out)
    conv_silu_kernel<<<(M * (DINNER / 4)) / 256, 256, 0, stream>>>(
        XZb, conv_w, conv_b, xcb);

    // 3) x_proj split-K partials
    xproj_part_kernel<<<dim3(M / 64, KSPLIT), 256, 0, stream>>>(xcb, W_x, part);

    // 4) delta (+ fused partial reduction, + B/C reduce -> xBC)
    delta_fused_kernel<<<dim3(DINNER / 64, M / 64), 256, 0, stream>>>(
        part, W_dt, b_dt, deltab, xBC);

    // 5) chunked selective scan
    scan_part1_kernel<<<dim3(DINNER / 256, 2, NCHUNK), 256, 0, stream>>>(
        deltab, xcb, xBC, A_log, Pbuf, Hbuf);
    scan_combine_kernel<<<(2 * DINNER * NSTATE) / 256, 256, 0, stream>>>(
        Pbuf, Hbuf, h0);
    scan_part2_kernel<<<dim3(DINNER / 256, 2, NCHUNK), 256, 0, stream>>>(
        deltab, xcb, xBC, h0, XZb, yb, A_log, D_skip);

    // 6) out_proj: direct 64x64 tiles, 512 blocks, ROW-band swizzle
    //    (per XCD: 4 A-panels 1MB + B 4MB ~= fits private L2)
    mfma_gemm_kernel<64, 64, 64, false, 2>
        <<<dim3(DMODEL / 64, M / 64), 256, 0, stream>>>(
            yb, Wbout, pout, nullptr, M, DMODEL, DINNER);

    // 7) LayerNorm -> d_out
    ln_kernel<<<M, 256, 0, stream>>>(pout, ln_g, ln_b, (float*)d_out);
}

// Round 10
// 274.904 us; speedup vs baseline: 1.0323x; 1.0323x over previous
//
#include <hip/hip_runtime.h>

// Mamba block fwd: B=2, L=1024, D=1024, DIN=2048, N=16, R=64, K=4
#define LSEQ 1024
#define DMODEL 1024
#define DINNER 2048
#define NSTATE 16
#define RRANK 64
#define CHUNK 32     // timesteps per scan chunk
#define NCHUNK 32    // LSEQ / CHUNK
#define KSPLIT 8     // xproj split-K factor
#define MF (1024 * 1024)   // 1M floats

typedef unsigned short u16;
typedef __attribute__((ext_vector_type(8))) short bf16x8;   // 8 bf16 = 4 VGPRs
typedef __attribute__((ext_vector_type(4))) short bf16x4;
typedef __attribute__((ext_vector_type(4))) float f32x4;

__device__ __forceinline__ float sigmoidf_(float x) {
    return 1.0f / (1.0f + __expf(-x));
}
__device__ __forceinline__ float softplusf_(float x) {
    return (x > 20.0f) ? x : log1pf(__expf(x));
}
__device__ __forceinline__ short f2bf(float f) {
    union { float f; unsigned u; } v; v.f = f;
    unsigned r = v.u + 0x7FFF + ((v.u >> 16) & 1);   // RNE
    return (short)(r >> 16);
}
__device__ __forceinline__ float bf2f(u16 b) {
    union { unsigned u; float f; } v; v.u = ((unsigned)b) << 16;
    return v.f;
}
// Async global->LDS, 16 B per lane; LDS dest = wave-uniform base + lane*16.
__device__ __forceinline__ void async_cp16(const u16* g, u16* l) {
    __builtin_amdgcn_global_load_lds(
        (const __attribute__((address_space(1))) unsigned int*)g,
        (__attribute__((address_space(3))) unsigned int*)l, 16, 0, 0);
}

// ---------------------------------------------------------------------------
// ALL input casts in ONE dispatch:
//  seg0 (1024 blk): x [2048,1024] -> xb bf16 (flat, 8/thread)
//  seg1 (4096 blk): W_in [1024,4096] -> W_in^T bf16 [4096,1024]
//  seg2 (2048 blk): W_out [2048,1024] -> W_out^T bf16 [1024,2048]
//  seg3 ( 128 blk): W_dt [64,2048]   -> W_dt^T bf16 [2048,64]
// ---------------------------------------------------------------------------
__global__ __launch_bounds__(256) void cast_all_kernel(
    const float* __restrict__ x, u16* __restrict__ xb,
    const float* __restrict__ Win, u16* __restrict__ Wbin,
    const float* __restrict__ Wout, u16* __restrict__ Wbout,
    const float* __restrict__ Wdt, u16* __restrict__ Wdtt)
{
    __shared__ float t[32][33];
    int bid = blockIdx.x;
    if (bid < 1024) {                               // flat cast
        const size_t i = ((size_t)bid * 256 + threadIdx.x) * 8;
        float4 a = *(const float4*)&x[i];
        float4 b = *(const float4*)&x[i + 4];
        bf16x8 o;
        o[0] = f2bf(a.x); o[1] = f2bf(a.y); o[2] = f2bf(a.z); o[3] = f2bf(a.w);
        o[4] = f2bf(b.x); o[5] = f2bf(b.y); o[6] = f2bf(b.z); o[7] = f2bf(b.w);
        *(bf16x8*)&xb[i] = o;
        return;
    }
    const float* in; u16* out; int R, C, bxi, byi;
    if (bid < 1024 + 4096) {
        int tt = bid - 1024;
        in = Win; out = Wbin; R = DMODEL; C = 2 * DINNER;
        bxi = tt & 127; byi = tt >> 7;
    } else if (bid < 1024 + 4096 + 2048) {
        int tt = bid - 5120;
        in = Wout; out = Wbout; R = DINNER; C = DMODEL;
        bxi = tt & 31; byi = tt >> 5;
    } else {
        int tt = bid - 7168;
        in = Wdt; out = Wdtt; R = RRANK; C = DINNER;
        bxi = tt & 63; byi = tt >> 6;               // 64 x 2 tiles
    }
    const int bx = bxi * 32, by = byi * 32;
    const int tx = threadIdx.x & 31, ty = threadIdx.x >> 5;
    #pragma unroll
    for (int i = 0; i < 4; ++i)
        t[ty + 8 * i][tx] = in[(size_t)(by + ty + 8 * i) * C + bx + tx];
    __syncthreads();
    #pragma unroll
    for (int i = 0; i < 4; ++i)
        out[(size_t)(bx + ty + 8 * i) * R + by + tx] = (u16)f2bf(t[tx][ty + 8 * i]);
}

// ---------------------------------------------------------------------------
// bf16 MFMA GEMM: A[M,K] * Bt[N,K]^T.  Async global_load_lds staging, BK=64.
// EPI: 0 = fp32 to Cf;  1 = bf16 to Cb;  2 = bf16 softplus(acc + bias[col]).
// BM x BN tile, 4 waves (2m x 2n), 16x16x32 bf16 MFMA.
// A/B-frag [mn=lane&15][k=quad*8+j]; C/D row=quad*4+reg, col=lane&15 (verified).
// NOTE (R9): XCD band swizzle measured -6us — natural dispatch order wins; removed.
// NOTE (R9): fusing the partial-reduce into delta re-did it 32x — un-fused.
// ---------------------------------------------------------------------------
template<int BM, int BN, int BK, int EPI>
__global__ __launch_bounds__(256) void mfma_gemm_kernel(
    const u16* __restrict__ A, const u16* __restrict__ Bt,
    float* __restrict__ Cf, u16* __restrict__ Cb,
    const float* __restrict__ bias, int M, int N, int K)
{
    constexpr int WMS = BM / 32;
    constexpr int WNS = BN / 32;
    __shared__ u16 lA[BM * BK];
    __shared__ u16 lB[BN * BK];

    const int tid  = threadIdx.x;
    const int lane = tid & 63, wave = tid >> 6;
    const int quad = lane >> 4, l16 = lane & 15;
    const int wm   = (wave >> 1) * (BM / 2);
    const int wn   = (wave & 1) * (BN / 2);
    const int row0 = blockIdx.y * BM;
    const int col0 = blockIdx.x * BN;

    f32x4 acc[WMS][WNS];
    #pragma unroll
    for (int i = 0; i < WMS; ++i)
        #pragma unroll
        for (int j = 0; j < WNS; ++j)
            acc[i][j] = (f32x4){0.f, 0.f, 0.f, 0.f};

    for (int k0 = 0; k0 < K; k0 += BK) {
        #pragma unroll
        for (int t = 0; t < (BM * BK) / 2048; ++t) {     // A: 16B/lane chunks
            int c = tid + t * 256;
            int r = c / (BK / 8), kc = c % (BK / 8);
            async_cp16(&A[(size_t)(row0 + r) * K + k0 + kc * 8], &lA[c * 8]);
        }
        #pragma unroll
        for (int t = 0; t < (BN * BK) / 2048; ++t) {
            int c = tid + t * 256;
            int r = c / (BK / 8), kc = c % (BK / 8);
            async_cp16(&Bt[(size_t)(col0 + r) * K + k0 + kc * 8], &lB[c * 8]);
        }
        __syncthreads();   // vmcnt drained before barrier
        #pragma unroll
        for (int ks = 0; ks < BK; ks += 32) {
            bf16x8 af[WMS], bfr[WNS];
            #pragma unroll
            for (int i = 0; i < WMS; ++i)
                af[i] = *(bf16x8*)&lA[(wm + i * 16 + l16) * BK + ks + quad * 8];
            #pragma unroll
            for (int j = 0; j < WNS; ++j)
                bfr[j] = *(bf16x8*)&lB[(wn + j * 16 + l16) * BK + ks + quad * 8];
            #pragma unroll
            for (int i = 0; i < WMS; ++i)
                #pragma unroll
                for (int j = 0; j < WNS; ++j)
                    acc[i][j] = __builtin_amdgcn_mfma_f32_16x16x32_bf16(
                        af[i], bfr[j], acc[i][j], 0, 0, 0);
        }
        __syncthreads();
    }
    if (EPI == 0) {
        #pragma unroll
        for (int i = 0; i < WMS; ++i)
            #pragma unroll
            for (int j = 0; j < WNS; ++j)
                #pragma unroll
                for (int r = 0; r < 4; ++r)
                    Cf[(size_t)(row0 + wm + i * 16 + quad * 4 + r) * N
                       + col0 + wn + j * 16 + l16] = acc[i][j][r];
    } else if (EPI == 1) {
        #pragma unroll
        for (int i = 0; i < WMS; ++i)
            #pragma unroll
            for (int j = 0; j < WNS; ++j)
                #pragma unroll
                for (int r = 0; r < 4; ++r)
                    Cb[(size_t)(row0 + wm + i * 16 + quad * 4 + r) * N
                       + col0 + wn + j * 16 + l16] = (u16)f2bf(acc[i][j][r]);
    } else {
        #pragma unroll
        for (int j = 0; j < WNS; ++j) {
            float bj = bias[col0 + wn + j * 16 + l16];
            #pragma unroll
            for (int i = 0; i < WMS; ++i)
                #pragma unroll
                for (int r = 0; r < 4; ++r)
                    Cb[(size_t)(row0 + wm + i * 16 + quad * 4 + r) * N
                       + col0 + wn + j * 16 + l16]
                        = (u16)f2bf(softplusf_(acc[i][j][r] + bj));
        }
    }
}

// ---------------------------------------------------------------------------
// Causal depthwise conv (K=4) + SiLU. Reads XZb x-half (bf16, stride 4096),
// writes xconv bf16.
// ---------------------------------------------------------------------------
__global__ __launch_bounds__(256) void conv_silu_kernel(
    const u16* __restrict__ XZb, const float* __restrict__ cw,
    const float* __restrict__ cb, u16* __restrict__ xcb)
{
    const int idx = blockIdx.x * 256 + threadIdx.x;   // over B*L*(DIN/4)
    const int dq  = idx % (DINNER / 4);
    const int bl  = idx / (DINNER / 4);               // b*L + l
    const int l   = bl % LSEQ;
    const int d0  = dq * 4;

    const float4* cw4 = (const float4*)cw;
    const float4 W0 = cw4[d0 + 0];
    const float4 W1 = cw4[d0 + 1];
    const float4 W2 = cw4[d0 + 2];
    const float4 W3 = cw4[d0 + 3];
    float4 s = *(const float4*)&cb[d0];

    #pragma unroll
    for (int k = 0; k < 4; ++k) {
        int ls = l + k - 3;
        if (ls >= 0) {
            bf16x4 xv = *(const bf16x4*)&XZb[(size_t)(bl + k - 3) * (2 * DINNER) + d0];
            s.x = fmaf(bf2f((u16)xv[0]), ((const float*)&W0)[k], s.x);
            s.y = fmaf(bf2f((u16)xv[1]), ((const float*)&W1)[k], s.y);
            s.z = fmaf(bf2f((u16)xv[2]), ((const float*)&W2)[k], s.z);
            s.w = fmaf(bf2f((u16)xv[3]), ((const float*)&W3)[k], s.w);
        }
    }
    bf16x4 o;
    o[0] = f2bf(s.x * sigmoidf_(s.x));
    o[1] = f2bf(s.y * sigmoidf_(s.y));
    o[2] = f2bf(s.z * sigmoidf_(s.z));
    o[3] = f2bf(s.w * sigmoidf_(s.w));
    *(bf16x4*)&xcb[(size_t)idx * 4] = o;
}

// ---------------------------------------------------------------------------
// x_proj split-K, deterministic: each k-split writes its own partial.
// ---------------------------------------------------------------------------
__global__ __launch_bounds__(256) void xproj_part_kernel(
    const u16* __restrict__ xcb, const float* __restrict__ Wx,
    float* __restrict__ part)
{
    __shared__ float As[32][64 + 4];
    __shared__ float Ws[32][96 + 4];

    const int tid  = threadIdx.x;
    const int tx   = tid % 32;
    const int ty   = tid / 32;
    const int row0 = blockIdx.x * 64;
    const int k0   = blockIdx.y * (DINNER / KSPLIT);

    float acc[8][3];
    #pragma unroll
    for (int i = 0; i < 8; ++i) { acc[i][0] = 0.f; acc[i][1] = 0.f; acc[i][2] = 0.f; }

    for (int kt = 0; kt < DINNER / KSPLIT; kt += 32) {
        const int kb = k0 + kt;
        {   // 64 rows x 32 ks of bf16: 256 thr x 8 elems
            int m = tid >> 2, kq = tid & 3;
            bf16x8 v = *(const bf16x8*)&xcb[(size_t)(row0 + m) * DINNER + kb + kq * 8];
            #pragma unroll
            for (int j = 0; j < 8; ++j)
                As[kq * 8 + j][m] = bf2f((u16)v[j]);
        }
        #pragma unroll
        for (int i = 0; i < 3; ++i) {
            int lin = tid + i * 256;
            int kk = lin / 24, q = lin % 24;
            *(float4*)&Ws[kk][q * 4] = *(const float4*)&Wx[(size_t)(kb + kk) * 96 + q * 4];
        }
        __syncthreads();
        #pragma unroll 8
        for (int kk = 0; kk < 32; ++kk) {
            float a[8];
            *(float4*)&a[0] = *(const float4*)&As[kk][ty * 8];
            *(float4*)&a[4] = *(const float4*)&As[kk][ty * 8 + 4];
            float b0 = Ws[kk][tx], b1 = Ws[kk][tx + 32], b2 = Ws[kk][tx + 64];
            #pragma unroll
            for (int i = 0; i < 8; ++i) {
                acc[i][0] = fmaf(a[i], b0, acc[i][0]);
                acc[i][1] = fmaf(a[i], b1, acc[i][1]);
                acc[i][2] = fmaf(a[i], b2, acc[i][2]);
            }
        }
        __syncthreads();
    }
    float* po = part + (size_t)blockIdx.y * (2 * LSEQ * 96);
    #pragma unroll
    for (int i = 0; i < 8; ++i) {
        int r = row0 + ty * 8 + i;
        po[(size_t)r * 96 + tx]      = acc[i][0];
        po[(size_t)r * 96 + tx + 32] = acc[i][1];
        po[(size_t)r * 96 + tx + 64] = acc[i][2];
    }
}

// ---------------------------------------------------------------------------
// Reduce the 8 partials ONCE: dt cols [0,64) -> dtb bf16 [2048,64] (MFMA A
// operand for the delta GEMM), B/C cols [64,96) -> xBC fp32 [2048,32].
// ---------------------------------------------------------------------------
__global__ __launch_bounds__(256) void xproj_reduce_kernel(
    const float* __restrict__ part, u16* __restrict__ dtb,
    float* __restrict__ xBC)
{
    const int idx = blockIdx.x * 256 + threadIdx.x;   // [0, 2048*96)
    const int r = idx / 96, c = idx % 96;
    float s = 0.0f;
    #pragma unroll
    for (int k = 0; k < KSPLIT; ++k)
        s += part[(size_t)k * (2 * LSEQ * 96) + idx];
    if (c < RRANK) dtb[(size_t)r * RRANK + c] = (u16)f2bf(s);
    else           xBC[(size_t)r * 32 + (c - RRANK)] = s;
}

// ---------------------------------------------------------------------------
// Chunked selective scan — channel-per-thread, N=16 states in registers.
// ---------------------------------------------------------------------------
__global__ __launch_bounds__(256) void scan_part1_kernel(
    const u16* __restrict__ deltab, const u16* __restrict__ xcb,
    const float* __restrict__ xBC, const float* __restrict__ A_log,
    float* __restrict__ Pbuf, float* __restrict__ Hbuf)
{
    const int d  = blockIdx.x * 256 + threadIdx.x;
    const int b  = blockIdx.y;
    const int ch = blockIdx.z;

    float Aa[NSTATE];
    #pragma unroll
    for (int q = 0; q < 4; ++q) {
        float4 v = *(const float4*)&A_log[(size_t)d * NSTATE + q * 4];
        Aa[q * 4 + 0] = -__expf(v.x);
        Aa[q * 4 + 1] = -__expf(v.y);
        Aa[q * 4 + 2] = -__expf(v.z);
        Aa[q * 4 + 3] = -__expf(v.w);
    }
    float h[NSTATE], P[NSTATE];
    #pragma unroll
    for (int n = 0; n < NSTATE; ++n) { h[n] = 0.0f; P[n] = 1.0f; }

    const size_t row0 = (size_t)b * LSEQ + (size_t)ch * CHUNK;
    #pragma unroll 4
    for (int t = 0; t < CHUNK; ++t) {
        const size_t row = row0 + t;
        float dv  = bf2f(deltab[row * DINNER + d]);
        float xcv = bf2f(xcb[row * DINNER + d]);
        float du  = dv * xcv;
        const float4* br = (const float4*)&xBC[row * 32];   // wave-uniform
        float4 B4[4] = { br[0], br[1], br[2], br[3] };
        const float* Bv = (const float*)B4;
        #pragma unroll
        for (int n = 0; n < NSTATE; ++n) {
            float dA = __expf(dv * Aa[n]);
            h[n] = fmaf(dA, h[n], du * Bv[n]);
            P[n] *= dA;
        }
    }
    float* Pp = &Pbuf[(((size_t)ch * 2 + b) * DINNER + d) * NSTATE];
    float* Hp = &Hbuf[(((size_t)ch * 2 + b) * DINNER + d) * NSTATE];
    #pragma unroll
    for (int q = 0; q < 4; ++q) {
        *(float4*)&Pp[q * 4] = *(float4*)&P[q * 4];
        *(float4*)&Hp[q * 4] = *(float4*)&h[q * 4];
    }
}

// Phase 2: per (b,d,n) serial prefix over chunks -> chunk-start states h0.
__global__ __launch_bounds__(256) void scan_combine_kernel(
    const float* __restrict__ Pbuf, const float* __restrict__ Hbuf,
    float* __restrict__ h0buf)
{
    const int idx = blockIdx.x * 256 + threadIdx.x;   // (b*DIN+d)*N+n
    float H = 0.0f;
    #pragma unroll 8
    for (int cch = 0; cch < NCHUNK; ++cch) {
        const size_t g = (size_t)cch * (2 * DINNER * NSTATE) + idx;
        h0buf[g] = H;
        H = fmaf(Pbuf[g], H, Hbuf[g]);
    }
}

// Phase 3: resweep from h0; y = sum_n h[n]*C[n]; +D-skip, *silu(z); y -> bf16.
__global__ __launch_bounds__(256) void scan_part2_kernel(
    const u16* __restrict__ deltab, const u16* __restrict__ xcb,
    const float* __restrict__ xBC, const float* __restrict__ h0buf,
    const u16* __restrict__ XZb, u16* __restrict__ yb,
    const float* __restrict__ A_log, const float* __restrict__ Dskip)
{
    const int d  = blockIdx.x * 256 + threadIdx.x;
    const int b  = blockIdx.y;
    const int ch = blockIdx.z;

    float Aa[NSTATE];
    #pragma unroll
    for (int q = 0; q < 4; ++q) {
        float4 v = *(const float4*)&A_log[(size_t)d * NSTATE + q * 4];
        Aa[q * 4 + 0] = -__expf(v.x);
        Aa[q * 4 + 1] = -__expf(v.y);
        Aa[q * 4 + 2] = -__expf(v.z);
        Aa[q * 4 + 3] = -__expf(v.w);
    }
    const float Dd = Dskip[d];

    float h[NSTATE];
    const float* Hp = &h0buf[(((size_t)ch * 2 + b) * DINNER + d) * NSTATE];
    #pragma unroll
    for (int q = 0; q < 4; ++q)
        *(float4*)&h[q * 4] = *(const float4*)&Hp[q * 4];

    const size_t row0 = (size_t)b * LSEQ + (size_t)ch * CHUNK;
    #pragma unroll 2
    for (int t = 0; t < CHUNK; ++t) {
        const size_t row = row0 + t;
        float dv  = bf2f(deltab[row * DINNER + d]);
        float xcv = bf2f(xcb[row * DINNER + d]);
        float du  = dv * xcv;
        const float4* br = (const float4*)&xBC[row * 32];   // wave-uniform
        float4 BC[8] = { br[0], br[1], br[2], br[3], br[4], br[5], br[6], br[7] };
        const float* Bv = (const float*)BC;
        const float* Cv = Bv + NSTATE;
        float y = 0.0f;
        #pragma unroll
        for (int n = 0; n < NSTATE; ++n) {
            float dA = __expf(dv * Aa[n]);
            h[n] = fmaf(dA, h[n], du * Bv[n]);
            y = fmaf(h[n], Cv[n], y);
        }
        float zz = bf2f(XZb[row * (2 * DINNER) + DINNER + d]);
        float yv = (y + xcv * Dd) * (zz * sigmoidf_(zz));
        yb[row * DINNER + d] = (u16)f2bf(yv);
    }
}

// ---------------------------------------------------------------------------
// Post LayerNorm over D=1024. One block per row.
// ---------------------------------------------------------------------------
__global__ __launch_bounds__(256) void ln_kernel(
    const float* __restrict__ t, const float* __restrict__ g,
    const float* __restrict__ b, float* __restrict__ out)
{
    const int row = blockIdx.x;
    const int tid = threadIdx.x;
    float4 v = *(const float4*)&t[(size_t)row * DMODEL + tid * 4];
    float s = v.x + v.y + v.z + v.w;
    float q = v.x * v.x + v.y * v.y + v.z * v.z + v.w * v.w;
    #pragma unroll
    for (int m = 1; m < 64; m <<= 1) {
        s += __shfl_xor(s, m, 64);
        q += __shfl_xor(q, m, 64);
    }
    __shared__ float ss[4], qq[4];
    if ((tid & 63) == 0) { ss[tid >> 6] = s; qq[tid >> 6] = q; }
    __syncthreads();
    float S = ss[0] + ss[1] + ss[2] + ss[3];
    float Q = qq[0] + qq[1] + qq[2] + qq[3];
    float mu  = S * (1.0f / DMODEL);
    float var = Q * (1.0f / DMODEL) - mu * mu;
    float rs  = rsqrtf(var + 1e-5f);
    float4 gv = *(const float4*)&g[tid * 4];
    float4 bv = *(const float4*)&b[tid * 4];
    float4 o;
    o.x = (v.x - mu) * rs * gv.x + bv.x;
    o.y = (v.y - mu) * rs * gv.y + bv.y;
    o.z = (v.z - mu) * rs * gv.z + bv.z;
    o.w = (v.w - mu) * rs * gv.w + bv.w;
    *(float4*)&out[(size_t)row * DMODEL + tid * 4] = o;
}

// ---------------------------------------------------------------------------
extern "C" void kernel_launch(void* const* d_in, const int* in_sizes, int n_in,
                              void* d_out, int out_size, void* d_ws, size_t ws_size,
                              hipStream_t stream) {
    const float* x      = (const float*)d_in[0];
    const float* W_in   = (const float*)d_in[1];
    const float* conv_w = (const float*)d_in[2];
    const float* conv_b = (const float*)d_in[3];
    const float* W_x    = (const float*)d_in[4];
    const float* W_dt   = (const float*)d_in[5];
    const float* b_dt   = (const float*)d_in[6];
    const float* A_log  = (const float*)d_in[7];
    const float* D_skip = (const float*)d_in[8];
    const float* W_out  = (const float*)d_in[9];
    const float* ln_g   = (const float*)d_in[10];
    const float* ln_b   = (const float*)d_in[11];
    (void)in_sizes; (void)n_in; (void)out_size; (void)ws_size;

    const int M = 2 * LSEQ;  // B*L = 2048

    // Workspace layout (float offsets). ~18.2M floats = ~73 MB.
    float* ws     = (float*)d_ws;
    u16*   XZb    = (u16*)ws;                 // [0,4M f)   in_proj out bf16 (dead after scan2)
    u16*   xcb    = (u16*)(ws + 4 * MF);      // [4M,6M)    xconv bf16       (dead after scan2)
    u16*   deltab = (u16*)(ws + 6 * MF);      // [6M,8M)    delta bf16       (dead after scan2)
    float* part   = ws + 8 * (size_t)MF;      // [8M,9.5M)  xproj partials   (dead after reduce)
    float* Pbuf   = ws + 8 * (size_t)MF;      // [8M,10M)   after part dead
    float* Hbuf   = ws + 10 * (size_t)MF;     // [10M,12M)
    float* h0     = ws + 12 * (size_t)MF;     // [12M,14M)
    u16*   xb     = (u16*)(ws + 14 * MF);     // [14M,15M)  x bf16 (dead after in_proj)
    u16*   Wbin   = (u16*)(ws + 15 * MF);     // [15M,17M)  W_in^T (dead after in_proj)
    u16*   Wbout  = (u16*)(ws + 17 * MF);     // [17M,18M)
    float* xBC    = ws + 18 * (size_t)MF;     // [18M,18.0625M) reduced B/C fp32
    u16*   Wdtt   = (u16*)(ws + 18 * MF + 65536);   // [+64K f)  W_dt^T bf16 [2048,64]
    u16*   dtb    = (u16*)(ws + 18 * MF + 131072);  // [+64K f)  dt bf16 [2048,64]
    u16*   yb     = (u16*)(ws + 15 * MF);     // Wbin region (y bf16, after scan2)
    float* pout   = ws;                       // [0,2M f) out_proj fp32 (over dead XZb)

    // 0) all casts, one dispatch
    cast_all_kernel<<<1024 + 4096 + 2048 + 128, 256, 0, stream>>>(
        x, xb, W_in, Wbin, W_out, Wbout, W_dt, Wdtt);

    // 1) in_proj: XZb = xb @ W_in^T, bf16 out (512 blocks)
    mfma_gemm_kernel<128, 128, 64, 1>
        <<<dim3((2 * DINNER) / 128, M / 128), 256, 0, stream>>>(
            xb, Wbin, nullptr, XZb, nullptr, M, 2 * DINNER, DMODEL);

    // 2) causal depthwise conv + silu (bf16 in/out)
    conv_silu_kernel<<<(M * (DINNER / 4)) / 256, 256, 0, stream>>>(
        XZb, conv_w, conv_b, xcb);

    // 3) x_proj split-K partials, then ONE reduction -> dtb bf16 + xBC fp32
    xproj_part_kernel<<<dim3(M / 64, KSPLIT), 256, 0, stream>>>(xcb, W_x, part);
    xproj_reduce_kernel<<<(M * 96) / 256, 256, 0, stream>>>(part, dtb, xBC);

    // 4) delta = softplus(dtb @ W_dt^T + b_dt) -> bf16, via MFMA (K=64)
    mfma_gemm_kernel<128, 128, 64, 2>
        <<<dim3(DINNER / 128, M / 128), 256, 0, stream>>>(
            dtb, Wdtt, nullptr, deltab, b_dt, M, DINNER, RRANK);

    // 5) chunked selective scan
    scan_part1_kernel<<<dim3(DINNER / 256, 2, NCHUNK), 256, 0, stream>>>(
        deltab, xcb, xBC, A_log, Pbuf, Hbuf);
    scan_combine_kernel<<<(2 * DINNER * NSTATE) / 256, 256, 0, stream>>>(
        Pbuf, Hbuf, h0);
    scan_part2_kernel<<<dim3(DINNER / 256, 2, NCHUNK), 256, 0, stream>>>(
        deltab, xcb, xBC, h0, XZb, yb, A_log, D_skip);

    // 6) out_proj: direct 64x64 tiles (512 blocks)
    mfma_gemm_kernel<64, 64, 64, 0>
        <<<dim3(DMODEL / 64, M / 64), 256, 0, stream>>>(
            yb, Wbout, pout, nullptr, nullptr, M, DMODEL, DINNER);

    // 7) LayerNorm -> d_out
    ln_kernel<<<M, 256, 0, stream>>>(pout, ln_g, ln_b, (float*)d_out);
}

// Round 11
// 260.873 us; speedup vs baseline: 1.0878x; 1.0538x over previous
//
#include <hip/hip_runtime.h>

// Mamba block fwd: B=2, L=1024, D=1024, DIN=2048, N=16, R=64, K=4
#define LSEQ 1024
#define DMODEL 1024
#define DINNER 2048
#define NSTATE 16
#define RRANK 64
#define CHUNK 32     // timesteps per scan chunk
#define NCHUNK 32    // LSEQ / CHUNK
#define KSPLIT 8     // xproj split-K factor
#define MF (1024 * 1024)   // 1M floats

typedef unsigned short u16;
typedef __attribute__((ext_vector_type(8))) short bf16x8;   // 8 bf16 = 4 VGPRs
typedef __attribute__((ext_vector_type(4))) short bf16x4;
typedef __attribute__((ext_vector_type(4))) float f32x4;

__device__ __forceinline__ float sigmoidf_(float x) {
    return 1.0f / (1.0f + __expf(-x));
}
__device__ __forceinline__ float softplusf_(float x) {
    return (x > 20.0f) ? x : log1pf(__expf(x));
}
__device__ __forceinline__ short f2bf(float f) {
    union { float f; unsigned u; } v; v.f = f;
    unsigned r = v.u + 0x7FFF + ((v.u >> 16) & 1);   // RNE
    return (short)(r >> 16);
}
__device__ __forceinline__ float bf2f(u16 b) {
    union { unsigned u; float f; } v; v.u = ((unsigned)b) << 16;
    return v.f;
}
// Async global->LDS, 16 B per lane; LDS dest = wave-uniform base + lane*16.
__device__ __forceinline__ void async_cp16(const u16* g, u16* l) {
    __builtin_amdgcn_global_load_lds(
        (const __attribute__((address_space(1))) unsigned int*)g,
        (__attribute__((address_space(3))) unsigned int*)l, 16, 0, 0);
}

// ---------------------------------------------------------------------------
// ALL input casts in ONE dispatch:
//  seg0 (1024 blk): x [2048,1024] -> xb bf16 (flat, 8/thread)
//  seg1 (4096 blk): W_in [1024,4096] -> W_in^T bf16 [4096,1024]
//  seg2 (2048 blk): W_out [2048,1024] -> W_out^T bf16 [1024,2048]
//  seg3 ( 128 blk): W_dt [64,2048]   -> W_dt^T bf16 [2048,64]
//  seg4 ( 192 blk): W_x  [2048,96]   -> W_x^T  bf16 [96,2048]
// ---------------------------------------------------------------------------
__global__ __launch_bounds__(256) void cast_all_kernel(
    const float* __restrict__ x, u16* __restrict__ xb,
    const float* __restrict__ Win, u16* __restrict__ Wbin,
    const float* __restrict__ Wout, u16* __restrict__ Wbout,
    const float* __restrict__ Wdt, u16* __restrict__ Wdtt,
    const float* __restrict__ Wx, u16* __restrict__ Wxb)
{
    __shared__ float t[32][33];
    int bid = blockIdx.x;
    if (bid < 1024) {                               // flat cast
        const size_t i = ((size_t)bid * 256 + threadIdx.x) * 8;
        float4 a = *(const float4*)&x[i];
        float4 b = *(const float4*)&x[i + 4];
        bf16x8 o;
        o[0] = f2bf(a.x); o[1] = f2bf(a.y); o[2] = f2bf(a.z); o[3] = f2bf(a.w);
        o[4] = f2bf(b.x); o[5] = f2bf(b.y); o[6] = f2bf(b.z); o[7] = f2bf(b.w);
        *(bf16x8*)&xb[i] = o;
        return;
    }
    const float* in; u16* out; int R, C, bxi, byi;
    if (bid < 1024 + 4096) {
        int tt = bid - 1024;
        in = Win; out = Wbin; R = DMODEL; C = 2 * DINNER;
        bxi = tt & 127; byi = tt >> 7;
    } else if (bid < 1024 + 4096 + 2048) {
        int tt = bid - 5120;
        in = Wout; out = Wbout; R = DINNER; C = DMODEL;
        bxi = tt & 31; byi = tt >> 5;
    } else if (bid < 1024 + 4096 + 2048 + 128) {
        int tt = bid - 7168;
        in = Wdt; out = Wdtt; R = RRANK; C = DINNER;
        bxi = tt & 63; byi = tt >> 6;               // 64 x 2 tiles
    } else {
        int tt = bid - 7296;
        in = Wx; out = Wxb; R = DINNER; C = 96;
        bxi = tt % 3; byi = tt / 3;                 // 3 x 64 tiles
    }
    const int bx = bxi * 32, by = byi * 32;
    const int tx = threadIdx.x & 31, ty = threadIdx.x >> 5;
    #pragma unroll
    for (int i = 0; i < 4; ++i)
        t[ty + 8 * i][tx] = in[(size_t)(by + ty + 8 * i) * C + bx + tx];
    __syncthreads();
    #pragma unroll
    for (int i = 0; i < 4; ++i)
        out[(size_t)(bx + ty + 8 * i) * R + by + tx] = (u16)f2bf(t[tx][ty + 8 * i]);
}

// ---------------------------------------------------------------------------
// bf16 MFMA GEMM: A[M,K] * Bt[N,K]^T.  Async global_load_lds staging.
// KSPL-way split-K over blockIdx.z (fp32 partials at Cf + z*M*N).
// EPI: 0 = fp32 to Cf;  1 = bf16 to Cb;  2 = bf16 softplus(acc + bias[col]).
// BM x BN tile, 4 waves (2m x 2n), 16x16x32 bf16 MFMA.
// A/B-frag [mn=lane&15][k=quad*8+j]; C/D row=quad*4+reg, col=lane&15 (verified).
// NOTE (R9): XCD band swizzle measured -6us — natural order wins; removed.
// NOTE (R9): fusing the partial-reduce into a col-tiled consumer re-did it
//            32x — reduce exactly once.
// ---------------------------------------------------------------------------
template<int BM, int BN, int BK, int KSPL, int EPI>
__global__ __launch_bounds__(256) void mfma_gemm_kernel(
    const u16* __restrict__ A, const u16* __restrict__ Bt,
    float* __restrict__ Cf, u16* __restrict__ Cb,
    const float* __restrict__ bias, int M, int N, int K)
{
    constexpr int WMS = BM / 32;
    constexpr int WNS = BN / 32;
    __shared__ u16 lA[BM * BK];
    __shared__ u16 lB[BN * BK];

    const int tid  = threadIdx.x;
    const int lane = tid & 63, wave = tid >> 6;
    const int quad = lane >> 4, l16 = lane & 15;
    const int wm   = (wave >> 1) * (BM / 2);
    const int wn   = (wave & 1) * (BN / 2);
    const int row0 = blockIdx.y * BM;
    const int col0 = blockIdx.x * BN;
    const int Kz   = K / KSPL;
    const int kbeg = (KSPL > 1) ? blockIdx.z * Kz : 0;

    f32x4 acc[WMS][WNS];
    #pragma unroll
    for (int i = 0; i < WMS; ++i)
        #pragma unroll
        for (int j = 0; j < WNS; ++j)
            acc[i][j] = (f32x4){0.f, 0.f, 0.f, 0.f};

    for (int k0 = kbeg; k0 < kbeg + Kz; k0 += BK) {
        #pragma unroll
        for (int t = 0; t < (BM * BK) / 2048; ++t) {     // A: 16B/lane chunks
            int c = tid + t * 256;
            int r = c / (BK / 8), kc = c % (BK / 8);
            async_cp16(&A[(size_t)(row0 + r) * K + k0 + kc * 8], &lA[c * 8]);
        }
        #pragma unroll
        for (int t = 0; t < (BN * BK) / 2048; ++t) {
            int c = tid + t * 256;
            int r = c / (BK / 8), kc = c % (BK / 8);
            async_cp16(&Bt[(size_t)(col0 + r) * K + k0 + kc * 8], &lB[c * 8]);
        }
        __syncthreads();   // vmcnt drained before barrier
        #pragma unroll
        for (int ks = 0; ks < BK; ks += 32) {
            bf16x8 af[WMS], bfr[WNS];
            #pragma unroll
            for (int i = 0; i < WMS; ++i)
                af[i] = *(bf16x8*)&lA[(wm + i * 16 + l16) * BK + ks + quad * 8];
            #pragma unroll
            for (int j = 0; j < WNS; ++j)
                bfr[j] = *(bf16x8*)&lB[(wn + j * 16 + l16) * BK + ks + quad * 8];
            #pragma unroll
            for (int i = 0; i < WMS; ++i)
                #pragma unroll
                for (int j = 0; j < WNS; ++j)
                    acc[i][j] = __builtin_amdgcn_mfma_f32_16x16x32_bf16(
                        af[i], bfr[j], acc[i][j], 0, 0, 0);
        }
        __syncthreads();
    }
    if (EPI == 0) {
        float* Cp = Cf + (size_t)((KSPL > 1) ? blockIdx.z : 0) * M * N;
        #pragma unroll
        for (int i = 0; i < WMS; ++i)
            #pragma unroll
            for (int j = 0; j < WNS; ++j)
                #pragma unroll
                for (int r = 0; r < 4; ++r)
                    Cp[(size_t)(row0 + wm + i * 16 + quad * 4 + r) * N
                       + col0 + wn + j * 16 + l16] = acc[i][j][r];
    } else if (EPI == 1) {
        #pragma unroll
        for (int i = 0; i < WMS; ++i)
            #pragma unroll
            for (int j = 0; j < WNS; ++j)
                #pragma unroll
                for (int r = 0; r < 4; ++r)
                    Cb[(size_t)(row0 + wm + i * 16 + quad * 4 + r) * N
                       + col0 + wn + j * 16 + l16] = (u16)f2bf(acc[i][j][r]);
    } else {
        #pragma unroll
        for (int j = 0; j < WNS; ++j) {
            float bj = bias[col0 + wn + j * 16 + l16];
            #pragma unroll
            for (int i = 0; i < WMS; ++i)
                #pragma unroll
                for (int r = 0; r < 4; ++r)
                    Cb[(size_t)(row0 + wm + i * 16 + quad * 4 + r) * N
                       + col0 + wn + j * 16 + l16]
                        = (u16)f2bf(softplusf_(acc[i][j][r] + bj));
        }
    }
}

// ---------------------------------------------------------------------------
// Causal depthwise conv (K=4) + SiLU. Reads XZb x-half (bf16, stride 4096),
// writes xconv bf16.
// ---------------------------------------------------------------------------
__global__ __launch_bounds__(256) void conv_silu_kernel(
    const u16* __restrict__ XZb, const float* __restrict__ cw,
    const float* __restrict__ cb, u16* __restrict__ xcb)
{
    const int idx = blockIdx.x * 256 + threadIdx.x;   // over B*L*(DIN/4)
    const int dq  = idx % (DINNER / 4);
    const int bl  = idx / (DINNER / 4);               // b*L + l
    const int l   = bl % LSEQ;
    const int d0  = dq * 4;

    const float4* cw4 = (const float4*)cw;
    const float4 W0 = cw4[d0 + 0];
    const float4 W1 = cw4[d0 + 1];
    const float4 W2 = cw4[d0 + 2];
    const float4 W3 = cw4[d0 + 3];
    float4 s = *(const float4*)&cb[d0];

    #pragma unroll
    for (int k = 0; k < 4; ++k) {
        int ls = l + k - 3;
        if (ls >= 0) {
            bf16x4 xv = *(const bf16x4*)&XZb[(size_t)(bl + k - 3) * (2 * DINNER) + d0];
            s.x = fmaf(bf2f((u16)xv[0]), ((const float*)&W0)[k], s.x);
            s.y = fmaf(bf2f((u16)xv[1]), ((const float*)&W1)[k], s.y);
            s.z = fmaf(bf2f((u16)xv[2]), ((const float*)&W2)[k], s.z);
            s.w = fmaf(bf2f((u16)xv[3]), ((const float*)&W3)[k], s.w);
        }
    }
    bf16x4 o;
    o[0] = f2bf(s.x * sigmoidf_(s.x));
    o[1] = f2bf(s.y * sigmoidf_(s.y));
    o[2] = f2bf(s.z * sigmoidf_(s.z));
    o[3] = f2bf(s.w * sigmoidf_(s.w));
    *(bf16x4*)&xcb[(size_t)idx * 4] = o;
}

// ---------------------------------------------------------------------------
// Reduce the 8 xproj partials ONCE: dt cols [0,64) -> dtb bf16 [2048,64]
// (MFMA A operand for delta GEMM), B/C cols [64,96) -> xBC fp32 [2048,32].
// ---------------------------------------------------------------------------
__global__ __launch_bounds__(256) void xproj_reduce_kernel(
    const float* __restrict__ part, u16* __restrict__ dtb,
    float* __restrict__ xBC)
{
    const int idx = blockIdx.x * 256 + threadIdx.x;   // [0, 2048*96)
    const int r = idx / 96, c = idx % 96;
    float s = 0.0f;
    #pragma unroll
    for (int k = 0; k < KSPLIT; ++k)
        s += part[(size_t)k * (2 * LSEQ * 96) + idx];
    if (c < RRANK) dtb[(size_t)r * RRANK + c] = (u16)f2bf(s);
    else           xBC[(size_t)r * 32 + (c - RRANK)] = s;
}

// ---------------------------------------------------------------------------
// Chunked selective scan — channel-per-thread, N=16 states in registers.
// ---------------------------------------------------------------------------
__global__ __launch_bounds__(256) void scan_part1_kernel(
    const u16* __restrict__ deltab, const u16* __restrict__ xcb,
    const float* __restrict__ xBC, const float* __restrict__ A_log,
    float* __restrict__ Pbuf, float* __restrict__ Hbuf)
{
    const int d  = blockIdx.x * 256 + threadIdx.x;
    const int b  = blockIdx.y;
    const int ch = blockIdx.z;

    float Aa[NSTATE];
    #pragma unroll
    for (int q = 0; q < 4; ++q) {
        float4 v = *(const float4*)&A_log[(size_t)d * NSTATE + q * 4];
        Aa[q * 4 + 0] = -__expf(v.x);
        Aa[q * 4 + 1] = -__expf(v.y);
        Aa[q * 4 + 2] = -__expf(v.z);
        Aa[q * 4 + 3] = -__expf(v.w);
    }
    float h[NSTATE], P[NSTATE];
    #pragma unroll
    for (int n = 0; n < NSTATE; ++n) { h[n] = 0.0f; P[n] = 1.0f; }

    const size_t row0 = (size_t)b * LSEQ + (size_t)ch * CHUNK;
    #pragma unroll 4
    for (int t = 0; t < CHUNK; ++t) {
        const size_t row = row0 + t;
        float dv  = bf2f(deltab[row * DINNER + d]);
        float xcv = bf2f(xcb[row * DINNER + d]);
        float du  = dv * xcv;
        const float4* br = (const float4*)&xBC[row * 32];   // wave-uniform
        float4 B4[4] = { br[0], br[1], br[2], br[3] };
        const float* Bv = (const float*)B4;
        #pragma unroll
        for (int n = 0; n < NSTATE; ++n) {
            float dA = __expf(dv * Aa[n]);
            h[n] = fmaf(dA, h[n], du * Bv[n]);
            P[n] *= dA;
        }
    }
    float* Pp = &Pbuf[(((size_t)ch * 2 + b) * DINNER + d) * NSTATE];
    float* Hp = &Hbuf[(((size_t)ch * 2 + b) * DINNER + d) * NSTATE];
    #pragma unroll
    for (int q = 0; q < 4; ++q) {
        *(float4*)&Pp[q * 4] = *(float4*)&P[q * 4];
        *(float4*)&Hp[q * 4] = *(float4*)&h[q * 4];
    }
}

// Phase 2: per (b,d,n) serial prefix over chunks -> chunk-start states h0.
__global__ __launch_bounds__(256) void scan_combine_kernel(
    const float* __restrict__ Pbuf, const float* __restrict__ Hbuf,
    float* __restrict__ h0buf)
{
    const int idx = blockIdx.x * 256 + threadIdx.x;   // (b*DIN+d)*N+n
    float H = 0.0f;
    #pragma unroll 8
    for (int cch = 0; cch < NCHUNK; ++cch) {
        const size_t g = (size_t)cch * (2 * DINNER * NSTATE) + idx;
        h0buf[g] = H;
        H = fmaf(Pbuf[g], H, Hbuf[g]);
    }
}

// Phase 3: resweep from h0; y = sum_n h[n]*C[n]; +D-skip, *silu(z); y -> bf16.
__global__ __launch_bounds__(256) void scan_part2_kernel(
    const u16* __restrict__ deltab, const u16* __restrict__ xcb,
    const float* __restrict__ xBC, const float* __restrict__ h0buf,
    const u16* __restrict__ XZb, u16* __restrict__ yb,
    const float* __restrict__ A_log, const float* __restrict__ Dskip)
{
    const int d  = blockIdx.x * 256 + threadIdx.x;
    const int b  = blockIdx.y;
    const int ch = blockIdx.z;

    float Aa[NSTATE];
    #pragma unroll
    for (int q = 0; q < 4; ++q) {
        float4 v = *(const float4*)&A_log[(size_t)d * NSTATE + q * 4];
        Aa[q * 4 + 0] = -__expf(v.x);
        Aa[q * 4 + 1] = -__expf(v.y);
        Aa[q * 4 + 2] = -__expf(v.z);
        Aa[q * 4 + 3] = -__expf(v.w);
    }
    const float Dd = Dskip[d];

    float h[NSTATE];
    const float* Hp = &h0buf[(((size_t)ch * 2 + b) * DINNER + d) * NSTATE];
    #pragma unroll
    for (int q = 0; q < 4; ++q)
        *(float4*)&h[q * 4] = *(const float4*)&Hp[q * 4];

    const size_t row0 = (size_t)b * LSEQ + (size_t)ch * CHUNK;
    #pragma unroll 2
    for (int t = 0; t < CHUNK; ++t) {
        const size_t row = row0 + t;
        float dv  = bf2f(deltab[row * DINNER + d]);
        float xcv = bf2f(xcb[row * DINNER + d]);
        float du  = dv * xcv;
        const float4* br = (const float4*)&xBC[row * 32];   // wave-uniform
        float4 BC[8] = { br[0], br[1], br[2], br[3], br[4], br[5], br[6], br[7] };
        const float* Bv = (const float*)BC;
        const float* Cv = Bv + NSTATE;
        float y = 0.0f;
        #pragma unroll
        for (int n = 0; n < NSTATE; ++n) {
            float dA = __expf(dv * Aa[n]);
            h[n] = fmaf(dA, h[n], du * Bv[n]);
            y = fmaf(h[n], Cv[n], y);
        }
        float zz = bf2f(XZb[row * (2 * DINNER) + DINNER + d]);
        float yv = (y + xcv * Dd) * (zz * sigmoidf_(zz));
        yb[row * DINNER + d] = (u16)f2bf(yv);
    }
}

// ---------------------------------------------------------------------------
// Post LayerNorm over D=1024. One block per row.
// ---------------------------------------------------------------------------
__global__ __launch_bounds__(256) void ln_kernel(
    const float* __restrict__ t, const float* __restrict__ g,
    const float* __restrict__ b, float* __restrict__ out)
{
    const int row = blockIdx.x;
    const int tid = threadIdx.x;
    float4 v = *(const float4*)&t[(size_t)row * DMODEL + tid * 4];
    float s = v.x + v.y + v.z + v.w;
    float q = v.x * v.x + v.y * v.y + v.z * v.z + v.w * v.w;
    #pragma unroll
    for (int m = 1; m < 64; m <<= 1) {
        s += __shfl_xor(s, m, 64);
        q += __shfl_xor(q, m, 64);
    }
    __shared__ float ss[4], qq[4];
    if ((tid & 63) == 0) { ss[tid >> 6] = s; qq[tid >> 6] = q; }
    __syncthreads();
    float S = ss[0] + ss[1] + ss[2] + ss[3];
    float Q = qq[0] + qq[1] + qq[2] + qq[3];
    float mu  = S * (1.0f / DMODEL);
    float var = Q * (1.0f / DMODEL) - mu * mu;
    float rs  = rsqrtf(var + 1e-5f);
    float4 gv = *(const float4*)&g[tid * 4];
    float4 bv = *(const float4*)&b[tid * 4];
    float4 o;
    o.x = (v.x - mu) * rs * gv.x + bv.x;
    o.y = (v.y - mu) * rs * gv.y + bv.y;
    o.z = (v.z - mu) * rs * gv.z + bv.z;
    o.w = (v.w - mu) * rs * gv.w + bv.w;
    *(float4*)&out[(size_t)row * DMODEL + tid * 4] = o;
}

// ---------------------------------------------------------------------------
extern "C" void kernel_launch(void* const* d_in, const int* in_sizes, int n_in,
                              void* d_out, int out_size, void* d_ws, size_t ws_size,
                              hipStream_t stream) {
    const float* x      = (const float*)d_in[0];
    const float* W_in   = (const float*)d_in[1];
    const float* conv_w = (const float*)d_in[2];
    const float* conv_b = (const float*)d_in[3];
    const float* W_x    = (const float*)d_in[4];
    const float* W_dt   = (const float*)d_in[5];
    const float* b_dt   = (const float*)d_in[6];
    const float* A_log  = (const float*)d_in[7];
    const float* D_skip = (const float*)d_in[8];
    const float* W_out  = (const float*)d_in[9];
    const float* ln_g   = (const float*)d_in[10];
    const float* ln_b   = (const float*)d_in[11];
    (void)in_sizes; (void)n_in; (void)out_size; (void)ws_size;

    const int M = 2 * LSEQ;  // B*L = 2048

    // Workspace layout (float offsets). ~18.3M floats = ~73.3 MB.
    float* ws     = (float*)d_ws;
    u16*   XZb    = (u16*)ws;                 // [0,4M f)   in_proj out bf16 (dead after scan2)
    u16*   xcb    = (u16*)(ws + 4 * MF);      // [4M,6M)    xconv bf16       (dead after scan2)
    u16*   deltab = (u16*)(ws + 6 * MF);      // [6M,8M)    delta bf16       (dead after scan2)
    float* part   = ws + 8 * (size_t)MF;      // [8M,9.5M)  xproj partials   (dead after reduce)
    float* Pbuf   = ws + 8 * (size_t)MF;      // [8M,10M)   after part dead
    float* Hbuf   = ws + 10 * (size_t)MF;     // [10M,12M)
    float* h0     = ws + 12 * (size_t)MF;     // [12M,14M)
    u16*   xb     = (u16*)(ws + 14 * MF);     // [14M,15M)  x bf16 (dead after in_proj)
    u16*   Wbin   = (u16*)(ws + 15 * MF);     // [15M,17M)  W_in^T (dead after in_proj)
    u16*   Wbout  = (u16*)(ws + 17 * MF);     // [17M,18M)
    float* xBC    = ws + 18 * (size_t)MF;     // [+65536 f)  reduced B/C fp32
    u16*   Wdtt   = (u16*)(ws + 18 * MF + 65536);   // [+65536 f)  W_dt^T bf16 [2048,64]
    u16*   dtb    = (u16*)(ws + 18 * MF + 131072);  // [+65536 f)  dt bf16 [2048,64]
    u16*   Wxb    = (u16*)(ws + 18 * MF + 196608);  // [+98304 f)  W_x^T bf16 [96,2048]
    u16*   yb     = (u16*)(ws + 15 * MF);     // Wbin region (y bf16, after scan2)
    float* pout   = ws;                       // [0,2M f) out_proj fp32 (over dead XZb)

    // 0) all casts, one dispatch
    cast_all_kernel<<<1024 + 4096 + 2048 + 128 + 192, 256, 0, stream>>>(
        x, xb, W_in, Wbin, W_out, Wbout, W_dt, Wdtt, W_x, Wxb);

    // 1) in_proj: XZb = xb @ W_in^T, bf16 out (512 blocks)
    mfma_gemm_kernel<128, 128, 64, 1, 1>
        <<<dim3((2 * DINNER) / 128, M / 128), 256, 0, stream>>>(
            xb, Wbin, nullptr, XZb, nullptr, M, 2 * DINNER, DMODEL);

    // 2) causal depthwise conv + silu (bf16 in/out)
    conv_silu_kernel<<<(M * (DINNER / 4)) / 256, 256, 0, stream>>>(
        XZb, conv_w, conv_b, xcb);

    // 3) x_proj via MFMA, split-K=8 -> part[z][2048][96] (384 blocks),
    //    then ONE reduction -> dtb bf16 + xBC fp32
    mfma_gemm_kernel<128, 32, 64, KSPLIT, 0>
        <<<dim3(96 / 32, M / 128, KSPLIT), 256, 0, stream>>>(
            xcb, Wxb, part, nullptr, nullptr, M, 96, DINNER);
    xproj_reduce_kernel<<<(M * 96) / 256, 256, 0, stream>>>(part, dtb, xBC);

    // 4) delta = softplus(dtb @ W_dt^T + b_dt) -> bf16, via MFMA (K=64)
    mfma_gemm_kernel<128, 128, 64, 1, 2>
        <<<dim3(DINNER / 128, M / 128), 256, 0, stream>>>(
            dtb, Wdtt, nullptr, deltab, b_dt, M, DINNER, RRANK);

    // 5) chunked selective scan
    scan_part1_kernel<<<dim3(DINNER / 256, 2, NCHUNK), 256, 0, stream>>>(
        deltab, xcb, xBC, A_log, Pbuf, Hbuf);
    scan_combine_kernel<<<(2 * DINNER * NSTATE) / 256, 256, 0, stream>>>(
        Pbuf, Hbuf, h0);
    scan_part2_kernel<<<dim3(DINNER / 256, 2, NCHUNK), 256, 0, stream>>>(
        deltab, xcb, xBC, h0, XZb, yb, A_log, D_skip);

    // 6) out_proj: direct 64x64 tiles (512 blocks)
    mfma_gemm_kernel<64, 64, 64, 1, 0>
        <<<dim3(DMODEL / 64, M / 64), 256, 0, stream>>>(
            yb, Wbout, pout, nullptr, nullptr, M, DMODEL, DINNER);

    // 7) LayerNorm -> d_out
    ln_kernel<<<M, 256, 0, stream>>>(pout, ln_g, ln_b, (float*)d_out);
}

// Round 13
// 250.779 us; speedup vs baseline: 1.1316x; 1.0402x over previous
//
#include <hip/hip_runtime.h>

// Mamba block fwd: B=2, L=1024, D=1024, DIN=2048, N=16, R=64, K=4
#define LSEQ 1024
#define DMODEL 1024
#define DINNER 2048
#define NSTATE 16
#define RRANK 64
#define CHUNK 32     // timesteps per scan chunk
#define NCHUNK 32    // LSEQ / CHUNK
#define KSPLIT 8     // xproj split-K factor
#define MF (1024 * 1024)   // 1M floats

typedef unsigned short u16;
typedef __attribute__((ext_vector_type(8))) short bf16x8;   // 8 bf16 = 4 VGPRs
typedef __attribute__((ext_vector_type(4))) short bf16x4;
typedef __attribute__((ext_vector_type(4))) float f32x4;

__device__ __forceinline__ float sigmoidf_(float x) {
    return 1.0f / (1.0f + __expf(-x));
}
__device__ __forceinline__ float softplusf_(float x) {
    return (x > 20.0f) ? x : log1pf(__expf(x));
}
__device__ __forceinline__ short f2bf(float f) {
    union { float f; unsigned u; } v; v.f = f;
    unsigned r = v.u + 0x7FFF + ((v.u >> 16) & 1);   // RNE
    return (short)(r >> 16);
}
__device__ __forceinline__ float bf2f(u16 b) {
    union { unsigned u; float f; } v; v.u = ((unsigned)b) << 16;
    return v.f;
}
// Async global->LDS, 16 B per lane; LDS dest = wave-uniform base + lane*16.
__device__ __forceinline__ void async_cp16(const u16* g, u16* l) {
    __builtin_amdgcn_global_load_lds(
        (const __attribute__((address_space(1))) unsigned int*)g,
        (__attribute__((address_space(3))) unsigned int*)l, 16, 0, 0);
}

// ---------------------------------------------------------------------------
// ALL input casts in ONE dispatch:
//  seg0 (1024 blk): x [2048,1024] -> xb bf16 (flat, 8/thread)
//  seg1 (4096 blk): W_in [1024,4096] -> W_in^T bf16 [4096,1024]
//  seg2 (2048 blk): W_out [2048,1024] -> W_out^T bf16 [1024,2048]
//  seg3 ( 128 blk): W_dt [64,2048]   -> W_dt^T bf16 [2048,64]
//  seg4 ( 192 blk): W_x  [2048,96]   -> W_x^T  bf16 [96,2048]
// ---------------------------------------------------------------------------
__global__ __launch_bounds__(256) void cast_all_kernel(
    const float* __restrict__ x, u16* __restrict__ xb,
    const float* __restrict__ Win, u16* __restrict__ Wbin,
    const float* __restrict__ Wout, u16* __restrict__ Wbout,
    const float* __restrict__ Wdt, u16* __restrict__ Wdtt,
    const float* __restrict__ Wx, u16* __restrict__ Wxb)
{
    __shared__ float t[32][33];
    int bid = blockIdx.x;
    if (bid < 1024) {                               // flat cast
        const size_t i = ((size_t)bid * 256 + threadIdx.x) * 8;
        float4 a = *(const float4*)&x[i];
        float4 b = *(const float4*)&x[i + 4];
        bf16x8 o;
        o[0] = f2bf(a.x); o[1] = f2bf(a.y); o[2] = f2bf(a.z); o[3] = f2bf(a.w);
        o[4] = f2bf(b.x); o[5] = f2bf(b.y); o[6] = f2bf(b.z); o[7] = f2bf(b.w);
        *(bf16x8*)&xb[i] = o;
        return;
    }
    const float* in; u16* out; int R, C, bxi, byi;
    if (bid < 1024 + 4096) {
        int tt = bid - 1024;
        in = Win; out = Wbin; R = DMODEL; C = 2 * DINNER;
        bxi = tt & 127; byi = tt >> 7;
    } else if (bid < 1024 + 4096 + 2048) {
        int tt = bid - 5120;
        in = Wout; out = Wbout; R = DINNER; C = DMODEL;
        bxi = tt & 31; byi = tt >> 5;
    } else if (bid < 1024 + 4096 + 2048 + 128) {
        int tt = bid - 7168;
        in = Wdt; out = Wdtt; R = RRANK; C = DINNER;
        bxi = tt & 63; byi = tt >> 6;               // 64 x 2 tiles
    } else {
        int tt = bid - 7296;
        in = Wx; out = Wxb; R = DINNER; C = 96;
        bxi = tt % 3; byi = tt / 3;                 // 3 x 64 tiles
    }
    const int bx = bxi * 32, by = byi * 32;
    const int tx = threadIdx.x & 31, ty = threadIdx.x >> 5;
    #pragma unroll
    for (int i = 0; i < 4; ++i)
        t[ty + 8 * i][tx] = in[(size_t)(by + ty + 8 * i) * C + bx + tx];
    __syncthreads();
    #pragma unroll
    for (int i = 0; i < 4; ++i)
        out[(size_t)(bx + ty + 8 * i) * R + by + tx] = (u16)f2bf(t[tx][ty + 8 * i]);
}

// ---------------------------------------------------------------------------
// bf16 MFMA GEMM: A[M,K] * Bt[N,K]^T.  Async global_load_lds staging.
// KSPL-way split-K over blockIdx.z (fp32 partials at Cf + z*M*N).
// EPI: 0 = fp32 to Cf;  1 = bf16 to Cb;  2 = bf16 softplus(acc + bias[col]).
// BM x BN tile, 4 waves (2m x 2n), 16x16x32 bf16 MFMA.
// A/B-frag [mn=lane&15][k=quad*8+j]; C/D row=quad*4+reg, col=lane&15 (verified).
// NOTE (R5):  >=2 blocks/CU or the barrier drain is exposed.
// NOTE (R9):  XCD band swizzle measured -6us — natural order wins; removed.
// NOTE (R9):  fusing the partial-reduce into a col-tiled consumer re-did it
//             32x — reduce exactly once.
// NOTE (R12): hipLaunchCooperativeKernel produced zero output (launch error,
//             unchecked) — stick to <<<>>> dispatches.
// ---------------------------------------------------------------------------
template<int BM, int BN, int BK, int KSPL, int EPI>
__global__ __launch_bounds__(256) void mfma_gemm_kernel(
    const u16* __restrict__ A, const u16* __restrict__ Bt,
    float* __restrict__ Cf, u16* __restrict__ Cb,
    const float* __restrict__ bias, int M, int N, int K)
{
    constexpr int WMS = BM / 32;
    constexpr int WNS = BN / 32;
    __shared__ u16 lA[BM * BK];
    __shared__ u16 lB[BN * BK];

    const int tid  = threadIdx.x;
    const int lane = tid & 63, wave = tid >> 6;
    const int quad = lane >> 4, l16 = lane & 15;
    const int wm   = (wave >> 1) * (BM / 2);
    const int wn   = (wave & 1) * (BN / 2);
    const int row0 = blockIdx.y * BM;
    const int col0 = blockIdx.x * BN;
    const int Kz   = K / KSPL;
    const int kbeg = (KSPL > 1) ? blockIdx.z * Kz : 0;

    f32x4 acc[WMS][WNS];
    #pragma unroll
    for (int i = 0; i < WMS; ++i)
        #pragma unroll
        for (int j = 0; j < WNS; ++j)
            acc[i][j] = (f32x4){0.f, 0.f, 0.f, 0.f};

    for (int k0 = kbeg; k0 < kbeg + Kz; k0 += BK) {
        #pragma unroll
        for (int t = 0; t < (BM * BK) / 2048; ++t) {     // A: 16B/lane chunks
            int c = tid + t * 256;
            int r = c / (BK / 8), kc = c % (BK / 8);
            async_cp16(&A[(size_t)(row0 + r) * K + k0 + kc * 8], &lA[c * 8]);
        }
        #pragma unroll
        for (int t = 0; t < (BN * BK) / 2048; ++t) {
            int c = tid + t * 256;
            int r = c / (BK / 8), kc = c % (BK / 8);
            async_cp16(&Bt[(size_t)(col0 + r) * K + k0 + kc * 8], &lB[c * 8]);
        }
        __syncthreads();   // vmcnt drained before barrier
        #pragma unroll
        for (int ks = 0; ks < BK; ks += 32) {
            bf16x8 af[WMS], bfr[WNS];
            #pragma unroll
            for (int i = 0; i < WMS; ++i)
                af[i] = *(bf16x8*)&lA[(wm + i * 16 + l16) * BK + ks + quad * 8];
            #pragma unroll
            for (int j = 0; j < WNS; ++j)
                bfr[j] = *(bf16x8*)&lB[(wn + j * 16 + l16) * BK + ks + quad * 8];
            #pragma unroll
            for (int i = 0; i < WMS; ++i)
                #pragma unroll
                for (int j = 0; j < WNS; ++j)
                    acc[i][j] = __builtin_amdgcn_mfma_f32_16x16x32_bf16(
                        af[i], bfr[j], acc[i][j], 0, 0, 0);
        }
        __syncthreads();
    }
    if (EPI == 0) {
        float* Cp = Cf + (size_t)((KSPL > 1) ? blockIdx.z : 0) * M * N;
        #pragma unroll
        for (int i = 0; i < WMS; ++i)
            #pragma unroll
            for (int j = 0; j < WNS; ++j)
                #pragma unroll
                for (int r = 0; r < 4; ++r)
                    Cp[(size_t)(row0 + wm + i * 16 + quad * 4 + r) * N
                       + col0 + wn + j * 16 + l16] = acc[i][j][r];
    } else if (EPI == 1) {
        #pragma unroll
        for (int i = 0; i < WMS; ++i)
            #pragma unroll
            for (int j = 0; j < WNS; ++j)
                #pragma unroll
                for (int r = 0; r < 4; ++r)
                    Cb[(size_t)(row0 + wm + i * 16 + quad * 4 + r) * N
                       + col0 + wn + j * 16 + l16] = (u16)f2bf(acc[i][j][r]);
    } else {
        #pragma unroll
        for (int j = 0; j < WNS; ++j) {
            float bj = bias[col0 + wn + j * 16 + l16];
            #pragma unroll
            for (int i = 0; i < WMS; ++i)
                #pragma unroll
                for (int r = 0; r < 4; ++r)
                    Cb[(size_t)(row0 + wm + i * 16 + quad * 4 + r) * N
                       + col0 + wn + j * 16 + l16]
                        = (u16)f2bf(softplusf_(acc[i][j][r] + bj));
        }
    }
}

// ---------------------------------------------------------------------------
// Causal depthwise conv (K=4) + SiLU. Reads XZb x-half (bf16, stride 4096),
// writes xconv bf16.
// ---------------------------------------------------------------------------
__global__ __launch_bounds__(256) void conv_silu_kernel(
    const u16* __restrict__ XZb, const float* __restrict__ cw,
    const float* __restrict__ cb, u16* __restrict__ xcb)
{
    const int idx = blockIdx.x * 256 + threadIdx.x;   // over B*L*(DIN/4)
    const int dq  = idx % (DINNER / 4);
    const int bl  = idx / (DINNER / 4);               // b*L + l
    const int l   = bl % LSEQ;
    const int d0  = dq * 4;

    const float4* cw4 = (const float4*)cw;
    const float4 W0 = cw4[d0 + 0];
    const float4 W1 = cw4[d0 + 1];
    const float4 W2 = cw4[d0 + 2];
    const float4 W3 = cw4[d0 + 3];
    float4 s = *(const float4*)&cb[d0];

    #pragma unroll
    for (int k = 0; k < 4; ++k) {
        int ls = l + k - 3;
        if (ls >= 0) {
            bf16x4 xv = *(const bf16x4*)&XZb[(size_t)(bl + k - 3) * (2 * DINNER) + d0];
            s.x = fmaf(bf2f((u16)xv[0]), ((const float*)&W0)[k], s.x);
            s.y = fmaf(bf2f((u16)xv[1]), ((const float*)&W1)[k], s.y);
            s.z = fmaf(bf2f((u16)xv[2]), ((const float*)&W2)[k], s.z);
            s.w = fmaf(bf2f((u16)xv[3]), ((const float*)&W3)[k], s.w);
        }
    }
    bf16x4 o;
    o[0] = f2bf(s.x * sigmoidf_(s.x));
    o[1] = f2bf(s.y * sigmoidf_(s.y));
    o[2] = f2bf(s.z * sigmoidf_(s.z));
    o[3] = f2bf(s.w * sigmoidf_(s.w));
    *(bf16x4*)&xcb[(size_t)idx * 4] = o;
}

// ---------------------------------------------------------------------------
// Reduce the 8 xproj partials ONCE: dt cols [0,64) -> dtb bf16 [2048,64]
// (MFMA A operand for delta GEMM), B/C cols [64,96) -> xBC fp32 [2048,32].
// ---------------------------------------------------------------------------
__global__ __launch_bounds__(256) void xproj_reduce_kernel(
    const float* __restrict__ part, u16* __restrict__ dtb,
    float* __restrict__ xBC)
{
    const int idx = blockIdx.x * 256 + threadIdx.x;   // [0, 2048*96)
    const int r = idx / 96, c = idx % 96;
    float s = 0.0f;
    #pragma unroll
    for (int k = 0; k < KSPLIT; ++k)
        s += part[(size_t)k * (2 * LSEQ * 96) + idx];
    if (c < RRANK) dtb[(size_t)r * RRANK + c] = (u16)f2bf(s);
    else           xBC[(size_t)r * 32 + (c - RRANK)] = s;
}

// ---------------------------------------------------------------------------
// Chunked selective scan — channel-per-thread, N=16 states in registers.
// ---------------------------------------------------------------------------
__global__ __launch_bounds__(256) void scan_part1_kernel(
    const u16* __restrict__ deltab, const u16* __restrict__ xcb,
    const float* __restrict__ xBC, const float* __restrict__ A_log,
    float* __restrict__ Pbuf, float* __restrict__ Hbuf)
{
    const int d  = blockIdx.x * 256 + threadIdx.x;
    const int b  = blockIdx.y;
    const int ch = blockIdx.z;

    float Aa[NSTATE];
    #pragma unroll
    for (int q = 0; q < 4; ++q) {
        float4 v = *(const float4*)&A_log[(size_t)d * NSTATE + q * 4];
        Aa[q * 4 + 0] = -__expf(v.x);
        Aa[q * 4 + 1] = -__expf(v.y);
        Aa[q * 4 + 2] = -__expf(v.z);
        Aa[q * 4 + 3] = -__expf(v.w);
    }
    float h[NSTATE], P[NSTATE];
    #pragma unroll
    for (int n = 0; n < NSTATE; ++n) { h[n] = 0.0f; P[n] = 1.0f; }

    const size_t row0 = (size_t)b * LSEQ + (size_t)ch * CHUNK;
    #pragma unroll 4
    for (int t = 0; t < CHUNK; ++t) {
        const size_t row = row0 + t;
        float dv  = bf2f(deltab[row * DINNER + d]);
        float xcv = bf2f(xcb[row * DINNER + d]);
        float du  = dv * xcv;
        const float4* br = (const float4*)&xBC[row * 32];   // wave-uniform
        float4 B4[4] = { br[0], br[1], br[2], br[3] };
        const float* Bv = (const float*)B4;
        #pragma unroll
        for (int n = 0; n < NSTATE; ++n) {
            float dA = __expf(dv * Aa[n]);
            h[n] = fmaf(dA, h[n], du * Bv[n]);
            P[n] *= dA;
        }
    }
    float* Pp = &Pbuf[(((size_t)ch * 2 + b) * DINNER + d) * NSTATE];
    float* Hp = &Hbuf[(((size_t)ch * 2 + b) * DINNER + d) * NSTATE];
    #pragma unroll
    for (int q = 0; q < 4; ++q) {
        *(float4*)&Pp[q * 4] = *(float4*)&P[q * 4];
        *(float4*)&Hp[q * 4] = *(float4*)&h[q * 4];
    }
}

// Phase 2: per (b,d,n) serial prefix over chunks -> chunk-start states h0.
__global__ __launch_bounds__(256) void scan_combine_kernel(
    const float* __restrict__ Pbuf, const float* __restrict__ Hbuf,
    float* __restrict__ h0buf)
{
    const int idx = blockIdx.x * 256 + threadIdx.x;   // (b*DIN+d)*N+n
    float H = 0.0f;
    #pragma unroll 8
    for (int cch = 0; cch < NCHUNK; ++cch) {
        const size_t g = (size_t)cch * (2 * DINNER * NSTATE) + idx;
        h0buf[g] = H;
        H = fmaf(Pbuf[g], H, Hbuf[g]);
    }
}

// Phase 3: resweep from h0; y = sum_n h[n]*C[n]; +D-skip, *silu(z); y -> bf16.
__global__ __launch_bounds__(256) void scan_part2_kernel(
    const u16* __restrict__ deltab, const u16* __restrict__ xcb,
    const float* __restrict__ xBC, const float* __restrict__ h0buf,
    const u16* __restrict__ XZb, u16* __restrict__ yb,
    const float* __restrict__ A_log, const float* __restrict__ Dskip)
{
    const int d  = blockIdx.x * 256 + threadIdx.x;
    const int b  = blockIdx.y;
    const int ch = blockIdx.z;

    float Aa[NSTATE];
    #pragma unroll
    for (int q = 0; q < 4; ++q) {
        float4 v = *(const float4*)&A_log[(size_t)d * NSTATE + q * 4];
        Aa[q * 4 + 0] = -__expf(v.x);
        Aa[q * 4 + 1] = -__expf(v.y);
        Aa[q * 4 + 2] = -__expf(v.z);
        Aa[q * 4 + 3] = -__expf(v.w);
    }
    const float Dd = Dskip[d];

    float h[NSTATE];
    const float* Hp = &h0buf[(((size_t)ch * 2 + b) * DINNER + d) * NSTATE];
    #pragma unroll
    for (int q = 0; q < 4; ++q)
        *(float4*)&h[q * 4] = *(const float4*)&Hp[q * 4];

    const size_t row0 = (size_t)b * LSEQ + (size_t)ch * CHUNK;
    #pragma unroll 2
    for (int t = 0; t < CHUNK; ++t) {
        const size_t row = row0 + t;
        float dv  = bf2f(deltab[row * DINNER + d]);
        float xcv = bf2f(xcb[row * DINNER + d]);
        float du  = dv * xcv;
        const float4* br = (const float4*)&xBC[row * 32];   // wave-uniform
        float4 BC[8] = { br[0], br[1], br[2], br[3], br[4], br[5], br[6], br[7] };
        const float* Bv = (const float*)BC;
        const float* Cv = Bv + NSTATE;
        float y = 0.0f;
        #pragma unroll
        for (int n = 0; n < NSTATE; ++n) {
            float dA = __expf(dv * Aa[n]);
            h[n] = fmaf(dA, h[n], du * Bv[n]);
            y = fmaf(h[n], Cv[n], y);
        }
        float zz = bf2f(XZb[row * (2 * DINNER) + DINNER + d]);
        float yv = (y + xcv * Dd) * (zz * sigmoidf_(zz));
        yb[row * DINNER + d] = (u16)f2bf(yv);
    }
}

// ---------------------------------------------------------------------------
// Post LayerNorm over D=1024. One block per row.
// ---------------------------------------------------------------------------
__global__ __launch_bounds__(256) void ln_kernel(
    const float* __restrict__ t, const float* __restrict__ g,
    const float* __restrict__ b, float* __restrict__ out)
{
    const int row = blockIdx.x;
    const int tid = threadIdx.x;
    float4 v = *(const float4*)&t[(size_t)row * DMODEL + tid * 4];
    float s = v.x + v.y + v.z + v.w;
    float q = v.x * v.x + v.y * v.y + v.z * v.z + v.w * v.w;
    #pragma unroll
    for (int m = 1; m < 64; m <<= 1) {
        s += __shfl_xor(s, m, 64);
        q += __shfl_xor(q, m, 64);
    }
    __shared__ float ss[4], qq[4];
    if ((tid & 63) == 0) { ss[tid >> 6] = s; qq[tid >> 6] = q; }
    __syncthreads();
    float S = ss[0] + ss[1] + ss[2] + ss[3];
    float Q = qq[0] + qq[1] + qq[2] + qq[3];
    float mu  = S * (1.0f / DMODEL);
    float var = Q * (1.0f / DMODEL) - mu * mu;
    float rs  = rsqrtf(var + 1e-5f);
    float4 gv = *(const float4*)&g[tid * 4];
    float4 bv = *(const float4*)&b[tid * 4];
    float4 o;
    o.x = (v.x - mu) * rs * gv.x + bv.x;
    o.y = (v.y - mu) * rs * gv.y + bv.y;
    o.z = (v.z - mu) * rs * gv.z + bv.z;
    o.w = (v.w - mu) * rs * gv.w + bv.w;
    *(float4*)&out[(size_t)row * DMODEL + tid * 4] = o;
}

// ---------------------------------------------------------------------------
extern "C" void kernel_launch(void* const* d_in, const int* in_sizes, int n_in,
                              void* d_out, int out_size, void* d_ws, size_t ws_size,
                              hipStream_t stream) {
    const float* x      = (const float*)d_in[0];
    const float* W_in   = (const float*)d_in[1];
    const float* conv_w = (const float*)d_in[2];
    const float* conv_b = (const float*)d_in[3];
    const float* W_x    = (const float*)d_in[4];
    const float* W_dt   = (const float*)d_in[5];
    const float* b_dt   = (const float*)d_in[6];
    const float* A_log  = (const float*)d_in[7];
    const float* D_skip = (const float*)d_in[8];
    const float* W_out  = (const float*)d_in[9];
    const float* ln_g   = (const float*)d_in[10];
    const float* ln_b   = (const float*)d_in[11];
    (void)in_sizes; (void)n_in; (void)out_size; (void)ws_size;

    const int M = 2 * LSEQ;  // B*L = 2048

    // Workspace layout (float offsets). ~18.3M floats = ~73.3 MB.
    float* ws     = (float*)d_ws;
    u16*   XZb    = (u16*)ws;                 // [0,4M f)   in_proj out bf16 (dead after scan2)
    u16*   xcb    = (u16*)(ws + 4 * MF);      // [4M,6M)    xconv bf16       (dead after scan2)
    u16*   deltab = (u16*)(ws + 6 * MF);      // [6M,8M)    delta bf16       (dead after scan2)
    float* part   = ws + 8 * (size_t)MF;      // [8M,9.5M)  xproj partials   (dead after reduce)
    float* Pbuf   = ws + 8 * (size_t)MF;      // [8M,10M)   after part dead
    float* Hbuf   = ws + 10 * (size_t)MF;     // [10M,12M)
    float* h0     = ws + 12 * (size_t)MF;     // [12M,14M)
    u16*   xb     = (u16*)(ws + 14 * MF);     // [14M,15M)  x bf16 (dead after in_proj)
    u16*   Wbin   = (u16*)(ws + 15 * MF);     // [15M,17M)  W_in^T (dead after in_proj)
    u16*   Wbout  = (u16*)(ws + 17 * MF);     // [17M,18M)
    float* xBC    = ws + 18 * (size_t)MF;     // [+65536 f)  reduced B/C fp32
    u16*   Wdtt   = (u16*)(ws + 18 * MF + 65536);   // [+65536 f)  W_dt^T bf16 [2048,64]
    u16*   dtb    = (u16*)(ws + 18 * MF + 131072);  // [+65536 f)  dt bf16 [2048,64]
    u16*   Wxb    = (u16*)(ws + 18 * MF + 196608);  // [+98304 f)  W_x^T bf16 [96,2048]
    u16*   yb     = (u16*)(ws + 15 * MF);     // Wbin region (y bf16, after scan2)
    float* pout   = ws;                       // [0,2M f) out_proj fp32 (over dead XZb)

    // 0) all casts, one dispatch
    cast_all_kernel<<<1024 + 4096 + 2048 + 128 + 192, 256, 0, stream>>>(
        x, xb, W_in, Wbin, W_out, Wbout, W_dt, Wdtt, W_x, Wxb);

    // 1) in_proj: XZb = xb @ W_in^T, bf16 out (512 blocks)
    mfma_gemm_kernel<128, 128, 64, 1, 1>
        <<<dim3((2 * DINNER) / 128, M / 128), 256, 0, stream>>>(
            xb, Wbin, nullptr, XZb, nullptr, M, 2 * DINNER, DMODEL);

    // 2) causal depthwise conv + silu (bf16 in/out)
    conv_silu_kernel<<<(M * (DINNER / 4)) / 256, 256, 0, stream>>>(
        XZb, conv_w, conv_b, xcb);

    // 3) x_proj via MFMA, split-K=8 -> part[z][2048][96] (384 blocks),
    //    then ONE reduction -> dtb bf16 + xBC fp32
    mfma_gemm_kernel<128, 32, 64, KSPLIT, 0>
        <<<dim3(96 / 32, M / 128, KSPLIT), 256, 0, stream>>>(
            xcb, Wxb, part, nullptr, nullptr, M, 96, DINNER);
    xproj_reduce_kernel<<<(M * 96) / 256, 256, 0, stream>>>(part, dtb, xBC);

    // 4) delta = softplus(dtb @ W_dt^T + b_dt) -> bf16, via MFMA (K=64);
    //    128x64 tiles -> 512 blocks = 2 blocks/CU (R5 lesson)
    mfma_gemm_kernel<128, 64, 64, 1, 2>
        <<<dim3(DINNER / 64, M / 128), 256, 0, stream>>>(
            dtb, Wdtt, nullptr, deltab, b_dt, M, DINNER, RRANK);

    // 5) chunked selective scan
    scan_part1_kernel<<<dim3(DINNER / 256, 2, NCHUNK), 256, 0, stream>>>(
        deltab, xcb, xBC, A_log, Pbuf, Hbuf);
    scan_combine_kernel<<<(2 * DINNER * NSTATE) / 256, 256, 0, stream>>>(
        Pbuf, Hbuf, h0);
    scan_part2_kernel<<<dim3(DINNER / 256, 2, NCHUNK), 256, 0, stream>>>(
        deltab, xcb, xBC, h0, XZb, yb, A_log, D_skip);

    // 6) out_proj: direct 64x64 tiles (512 blocks)
    mfma_gemm_kernel<64, 64, 64, 1, 0>
        <<<dim3(DMODEL / 64, M / 64), 256, 0, stream>>>(
            yb, Wbout, pout, nullptr, nullptr, M, DMODEL, DINNER);

    // 7) LayerNorm -> d_out
    ln_kernel<<<M, 256, 0, stream>>>(pout, ln_g, ln_b, (float*)d_out);
}